// Round 15
// baseline (119.029 us; speedup 1.0000x reference)
//
#include <hip/hip_runtime.h>
#include <hip/hip_bf16.h>

#define BN 4
#define NN 4096
#define DD 128

typedef __attribute__((ext_vector_type(8))) __bf16 bf16x8;
typedef __attribute__((ext_vector_type(4))) float f32x4;

typedef union {
  bf16x8 v;
  unsigned int u[4];
  uint2 u2[2];
} pk8;

typedef __attribute__((address_space(1))) const unsigned int* gas_p;
typedef __attribute__((address_space(3))) unsigned int* las_p;

__device__ __forceinline__ void gload16(const void* g, void* l) {
  __builtin_amdgcn_global_load_lds((gas_p)g, (las_p)l, 16, 0, 0);
}
__device__ __forceinline__ void wait_vm0() {
  asm volatile("s_waitcnt vmcnt(0)" ::: "memory");
}
__device__ __forceinline__ void wait_vm2() {
  asm volatile("s_waitcnt vmcnt(2)" ::: "memory");
}
__device__ __forceinline__ unsigned int cvtpk(float lo, float hi) {
  unsigned int r;
  asm("v_cvt_pk_bf16_f32 %0, %1, %2" : "=v"(r) : "v"(lo), "v"(hi));
  return r;
}
__device__ __forceinline__ unsigned int pkrelu(float lo, float hi) {
  return cvtpk(fmaxf(lo, 0.f), fmaxf(hi, 0.f));
}

__device__ inline unsigned short f2bf(float f) {
  unsigned int u = __float_as_uint(f);
  unsigned int r = (u + 0x7FFFu + ((u >> 16) & 1u)) >> 16;
  return (unsigned short)r;
}
__device__ inline float bf2f(unsigned short s) {
  return __uint_as_float(((unsigned int)s) << 16);
}

// ---------------- kernel 1: cast x (fp32) -> xb (bf16) ----------------
__global__ __launch_bounds__(256) void k_cvt(const float* __restrict__ x,
                                             unsigned short* __restrict__ xb) {
  int i = (blockIdx.x * 256 + threadIdx.x) * 8;
  float4 a = *(const float4*)(x + i);
  float4 c = *(const float4*)(x + i + 4);
  uint4 o;
  o.x = cvtpk(a.x, a.y);
  o.y = cvtpk(a.z, a.w);
  o.z = cvtpk(c.x, c.y);
  o.w = cvtpk(c.z, c.w);
  *(uint4*)(xb + i) = o;
}

// ---- kernel 2: colpart[(ic*BN+b)][j] = sum_{i in chunk ic} relu(<x_i,x_j>) ----
// (round-12 proven version: LDS dbuf via global_load_lds, 4 blocks/CU)
__global__ __launch_bounds__(256, 4) void k_colsum(const unsigned short* __restrict__ xb,
                                                   float* __restrict__ colpart) {
  __shared__ unsigned short XiB[2][64 * 128];  // 32 KB
  const int b = blockIdx.y, j0 = blockIdx.x * 128, ic = blockIdx.z;
  const int tid = threadIdx.x, lane = tid & 63, wv = tid >> 6;
  const unsigned short* xbb = xb + b * NN * DD;
  const int g = lane >> 4;
  const int ibeg = ic * (NN / 8);
  const int nt = (NN / 8) / 64;  // 8

#pragma unroll
  for (int hb = 0; hb < 2; ++hb)
#pragma unroll
    for (int q = 0; q < 4; ++q) {
      int c = wv * 4 + q;
      int lr = c * 4 + g;
      int gsrc = (lane & 15) ^ (lr & 7);
      gload16(&xbb[(j0 + hb * 64 + lr) * 128 + gsrc * 8], &XiB[hb][c * 512]);
    }
  wait_vm0();
  __syncthreads();

  bf16x8 bfr[2][4];
#pragma unroll
  for (int ni = 0; ni < 2; ++ni)
#pragma unroll
    for (int kk = 0; kk < 4; ++kk) {
      int lr = (wv & 1) * 32 + ni * 16 + (lane & 15);
      bfr[ni][kk] = *(const bf16x8*)&XiB[wv >> 1][lr * 128 + (((kk * 4 + g) ^ (lr & 7)) << 3)];
    }
  __syncthreads();

#pragma unroll
  for (int q = 0; q < 4; ++q) {
    int c = wv * 4 + q;
    int lr = c * 4 + g;
    int gsrc = (lane & 15) ^ (lr & 7);
    gload16(&xbb[(ibeg + lr) * 128 + gsrc * 8], &XiB[1][c * 512]);
  }

  int basek[4];
#pragma unroll
  for (int kk = 0; kk < 4; ++kk)
    basek[kk] = (lane & 15) * 128 + (((kk * 4 + g) ^ (lane & 7)) << 3);

  float colacc0 = 0.f, colacc1 = 0.f;
  for (int t = 0; t < nt; ++t) {
    wait_vm0();
    __syncthreads();
    const int cur = (t + 1) & 1, nxt = t & 1;
    if (t + 1 < nt) {
      const int i1 = ibeg + (t + 1) * 64;
#pragma unroll
      for (int q = 0; q < 4; ++q) {
        int c = wv * 4 + q;
        int lr = c * 4 + g;
        int gsrc = (lane & 15) ^ (lr & 7);
        gload16(&xbb[(i1 + lr) * 128 + gsrc * 8], &XiB[nxt][c * 512]);
      }
    }
    f32x4 a0[4], a1[4];
#pragma unroll
    for (int mj = 0; mj < 4; ++mj) { a0[mj] = (f32x4){}; a1[mj] = (f32x4){}; }
    __builtin_amdgcn_s_setprio(1);
#pragma unroll
    for (int kk = 0; kk < 4; ++kk) {
      bf16x8 ar0 = *(const bf16x8*)&XiB[cur][basek[kk]];
      bf16x8 ar1 = *(const bf16x8*)&XiB[cur][basek[kk] + 1 * 2048];
      bf16x8 ar2 = *(const bf16x8*)&XiB[cur][basek[kk] + 2 * 2048];
      bf16x8 ar3 = *(const bf16x8*)&XiB[cur][basek[kk] + 3 * 2048];
      a0[0] = __builtin_amdgcn_mfma_f32_16x16x32_bf16(ar0, bfr[0][kk], a0[0], 0, 0, 0);
      a1[0] = __builtin_amdgcn_mfma_f32_16x16x32_bf16(ar0, bfr[1][kk], a1[0], 0, 0, 0);
      a0[1] = __builtin_amdgcn_mfma_f32_16x16x32_bf16(ar1, bfr[0][kk], a0[1], 0, 0, 0);
      a1[1] = __builtin_amdgcn_mfma_f32_16x16x32_bf16(ar1, bfr[1][kk], a1[1], 0, 0, 0);
      a0[2] = __builtin_amdgcn_mfma_f32_16x16x32_bf16(ar2, bfr[0][kk], a0[2], 0, 0, 0);
      a1[2] = __builtin_amdgcn_mfma_f32_16x16x32_bf16(ar2, bfr[1][kk], a1[2], 0, 0, 0);
      a0[3] = __builtin_amdgcn_mfma_f32_16x16x32_bf16(ar3, bfr[0][kk], a0[3], 0, 0, 0);
      a1[3] = __builtin_amdgcn_mfma_f32_16x16x32_bf16(ar3, bfr[1][kk], a1[3], 0, 0, 0);
    }
    __builtin_amdgcn_s_setprio(0);
    {
      float s0 = 0.f, s1 = 0.f;
#pragma unroll
      for (int mj = 0; mj < 4; ++mj)
#pragma unroll
        for (int r = 0; r < 4; ++r) {
          s0 += fmaxf(a0[mj][r], 0.f);
          s1 += fmaxf(a1[mj][r], 0.f);
        }
      s0 += __shfl_xor(s0, 16); s0 += __shfl_xor(s0, 32);
      s1 += __shfl_xor(s1, 16); s1 += __shfl_xor(s1, 32);
      colacc0 += s0; colacc1 += s1;
    }
  }
  if (lane < 16) {
    colpart[(ic * BN + b) * NN + j0 + wv * 32 + lane] = colacc0;
    colpart[(ic * BN + b) * NN + j0 + wv * 32 + 16 + lane] = colacc1;
  }
}

// ---- kernel 3: yt[b][d][j] = bf16(x[b][j][d] / sum_ic colpart) ----
__global__ __launch_bounds__(256) void k_ytrans(const float* __restrict__ x,
                                                const float* __restrict__ colpart,
                                                unsigned short* __restrict__ yt) {
  __shared__ unsigned short T[64 * 72];
  const int b = blockIdx.z, j0 = blockIdx.y * 64, d0 = blockIdx.x * 64;
  const int tid = threadIdx.x;
  int jr = tid >> 2, q0 = (tid & 3) * 16;
  float cs = 0.f;
#pragma unroll
  for (int ic = 0; ic < 8; ++ic) cs += colpart[(ic * BN + b) * NN + j0 + jr];
  float inv = 1.0f / cs;
  const float* xr = x + (size_t)(b * NN + j0 + jr) * DD + d0 + q0;
#pragma unroll
  for (int q = 0; q < 4; ++q) {
    float4 v = *(const float4*)(xr + q * 4);
    int dc = q0 + q * 4;
    T[jr * 72 + dc + 0] = f2bf(v.x * inv);
    T[jr * 72 + dc + 1] = f2bf(v.y * inv);
    T[jr * 72 + dc + 2] = f2bf(v.z * inv);
    T[jr * 72 + dc + 3] = f2bf(v.w * inv);
  }
  __syncthreads();
  for (int c = tid; c < 512; c += 256) {
    int dr = c >> 3, jg = c & 7;
    alignas(16) unsigned short tmp[8];
#pragma unroll
    for (int u = 0; u < 8; ++u) tmp[u] = T[(jg * 8 + u) * 72 + dr];
    *(uint4*)&yt[(size_t)(b * DD + d0 + dr) * NN + j0 + jg * 8] = *(const uint4*)tmp;
  }
}

// ---- kernel 4: opart[zc][b*NN+i][:] = sum_{j in chunk zc} relu(<x_i,x_j>) y[j][:] ----
// BM=256, 8 waves/block (512 thr): same 1-barrier/iter loop as round 12, but
// each staged Xj/Ys tile feeds 8 waves (2x MFMA per stage/barrier); Xi B-frags
// loaded once from global (contiguous 16B/lane). 80 KB LDS -> 2 blocks/CU =
// 4 waves/SIMD. Counted wait re-derived: vmcnt(2) keeps Ys[t+1] in flight.
__global__ __launch_bounds__(512, 4) void k_pass2(const unsigned short* __restrict__ xb,
                                                  const unsigned short* __restrict__ yt,
                                                  unsigned short* __restrict__ opart,
                                                  int jc) {
  __shared__ unsigned short XjB[2][64 * 128];  // 32 KB (epilogue sb rows 0-127)
  __shared__ unsigned short YsB[3][128 * 64];  // 48 KB (epilogue sb rows 128-255)
  const int b = blockIdx.y, i0 = blockIdx.x * 256, zc = blockIdx.z;
  const int tid = threadIdx.x, lane = tid & 63, wv = tid >> 6;  // wv 0..7
  const unsigned short* xbb = xb + b * NN * DD;
  const unsigned short* ytb = yt + (size_t)b * DD * NN;
  const int g = lane >> 4, l15 = lane & 15;

  const int jspan = NN / jc;
  const int jbeg = zc * jspan;
  const int nt = jspan / 64;

  // Xi B-frags (wave's 32 i-rows) straight from global: contiguous 16B/lane,
  // one-time, L2-hot. Same values as the old LDS-staged path.
  bf16x8 bfr[2][4];
#pragma unroll
  for (int ni = 0; ni < 2; ++ni)
#pragma unroll
    for (int kk = 0; kk < 4; ++kk)
      bfr[ni][kk] = *(const bf16x8*)&xbb[(size_t)(i0 + wv * 32 + ni * 16 + l15) * 128 +
                                         (kk * 4 + g) * 8];

  // issue tile0 (oldest-first): Xj0 -> XjB[0], Ys0 -> YsB[0], Ys1 -> YsB[1]
#pragma unroll
  for (int q = 0; q < 2; ++q) {
    int c = wv * 2 + q;
    int lr = c * 4 + g;
    int gsrc = l15 ^ (lr & 7);
    gload16(&xbb[(jbeg + lr) * 128 + gsrc * 8], &XjB[0][c * 512]);
  }
#pragma unroll
  for (int q = 0; q < 2; ++q) {
    int c = wv * 2 + q;
    int dr = c * 8 + (lane >> 3);
    int gsrc = (lane & 7) ^ (dr & 7);
    gload16(&ytb[(size_t)dr * NN + jbeg + gsrc * 8], &YsB[0][c * 512]);
  }
  if (1 < nt) {
#pragma unroll
    for (int q = 0; q < 2; ++q) {
      int c = wv * 2 + q;
      int dr = c * 8 + (lane >> 3);
      int gsrc = (lane & 7) ^ (dr & 7);
      gload16(&ytb[(size_t)dr * NN + jbeg + 64 + gsrc * 8], &YsB[1][c * 512]);
    }
  }

  int xjb[4];   // S^T A-frag bases in Xj tile
#pragma unroll
  for (int kk = 0; kk < 4; ++kk)
    xjb[kk] = l15 * 128 + (((kk * 4 + g) ^ (l15 & 7)) << 3);
  int ysb[2][2];  // PV B b64 offsets (within a Ys buffer)
#pragma unroll
  for (int c = 0; c < 2; ++c)
#pragma unroll
    for (int h = 0; h < 2; ++h) {
      int jq = c * 4 + 2 * h + (g >> 1);
      ysb[c][h] = l15 * 64 + ((jq ^ (l15 & 7)) << 3) + (g & 1) * 4;
    }

  f32x4 oacc0[8], oacc1[8];
#pragma unroll
  for (int n = 0; n < 8; ++n) { oacc0[n] = (f32x4){}; oacc1[n] = (f32x4){}; }

  int ybuf = 0;  // = t % 3
  for (int t = 0; t < nt; ++t) {
    // counted wait: keep Ys[t+1]'s 2 loads in flight except at the last iter
    if (t + 1 < nt) wait_vm2(); else wait_vm0();
    __syncthreads();
    // issue next tiles (Xj[t+1] first, then Ys[t+2] — oldest-first discipline)
    if (t + 1 < nt) {
      const int j1 = jbeg + (t + 1) * 64;
#pragma unroll
      for (int q = 0; q < 2; ++q) {
        int c = wv * 2 + q;
        int lr = c * 4 + g;
        int gsrc = l15 ^ (lr & 7);
        gload16(&xbb[(j1 + lr) * 128 + gsrc * 8], &XjB[(t + 1) & 1][c * 512]);
      }
      if (t + 2 < nt) {
        const int j2 = jbeg + (t + 2) * 64;
        int nb = ybuf + 2; if (nb >= 3) nb -= 3;
#pragma unroll
        for (int q = 0; q < 2; ++q) {
          int c = wv * 2 + q;
          int dr = c * 8 + (lane >> 3);
          int gsrc = (lane & 7) ^ (dr & 7);
          gload16(&ytb[(size_t)dr * NN + j2 + gsrc * 8], &YsB[nb][c * 512]);
        }
      }
    }
    const unsigned short* Xj = XjB[t & 1];
    const unsigned short* Ys = YsB[ybuf];

    f32x4 s0[4], s1[4];
#pragma unroll
    for (int mj = 0; mj < 4; ++mj) { s0[mj] = (f32x4){}; s1[mj] = (f32x4){}; }
    __builtin_amdgcn_s_setprio(1);
#pragma unroll
    for (int kk = 0; kk < 4; ++kk) {
      bf16x8 ar0 = *(const bf16x8*)&Xj[xjb[kk]];
      bf16x8 ar1 = *(const bf16x8*)&Xj[xjb[kk] + 1 * 2048];
      bf16x8 ar2 = *(const bf16x8*)&Xj[xjb[kk] + 2 * 2048];
      bf16x8 ar3 = *(const bf16x8*)&Xj[xjb[kk] + 3 * 2048];
      s0[0] = __builtin_amdgcn_mfma_f32_16x16x32_bf16(ar0, bfr[0][kk], s0[0], 0, 0, 0);
      s1[0] = __builtin_amdgcn_mfma_f32_16x16x32_bf16(ar0, bfr[1][kk], s1[0], 0, 0, 0);
      s0[1] = __builtin_amdgcn_mfma_f32_16x16x32_bf16(ar1, bfr[0][kk], s0[1], 0, 0, 0);
      s1[1] = __builtin_amdgcn_mfma_f32_16x16x32_bf16(ar1, bfr[1][kk], s1[1], 0, 0, 0);
      s0[2] = __builtin_amdgcn_mfma_f32_16x16x32_bf16(ar2, bfr[0][kk], s0[2], 0, 0, 0);
      s1[2] = __builtin_amdgcn_mfma_f32_16x16x32_bf16(ar2, bfr[1][kk], s1[2], 0, 0, 0);
      s0[3] = __builtin_amdgcn_mfma_f32_16x16x32_bf16(ar3, bfr[0][kk], s0[3], 0, 0, 0);
      s1[3] = __builtin_amdgcn_mfma_f32_16x16x32_bf16(ar3, bfr[1][kk], s1[3], 0, 0, 0);
    }
    __builtin_amdgcn_s_setprio(0);
    pk8 p00, p01, p10, p11;
    p00.u[0] = pkrelu(s0[0][0], s0[0][1]); p00.u[1] = pkrelu(s0[0][2], s0[0][3]);
    p00.u[2] = pkrelu(s0[1][0], s0[1][1]); p00.u[3] = pkrelu(s0[1][2], s0[1][3]);
    p01.u[0] = pkrelu(s1[0][0], s1[0][1]); p01.u[1] = pkrelu(s1[0][2], s1[0][3]);
    p01.u[2] = pkrelu(s1[1][0], s1[1][1]); p01.u[3] = pkrelu(s1[1][2], s1[1][3]);
    p10.u[0] = pkrelu(s0[2][0], s0[2][1]); p10.u[1] = pkrelu(s0[2][2], s0[2][3]);
    p10.u[2] = pkrelu(s0[3][0], s0[3][1]); p10.u[3] = pkrelu(s0[3][2], s0[3][3]);
    p11.u[0] = pkrelu(s1[2][0], s1[2][1]); p11.u[1] = pkrelu(s1[2][2], s1[2][3]);
    p11.u[2] = pkrelu(s1[3][0], s1[3][1]); p11.u[3] = pkrelu(s1[3][2], s1[3][3]);
    __builtin_amdgcn_s_setprio(1);
#pragma unroll
    for (int n = 0; n < 8; ++n) {
      pk8 bb0, bb1;
      bb0.u2[0] = *(const uint2*)&Ys[ysb[0][0] + n * 1024];
      bb0.u2[1] = *(const uint2*)&Ys[ysb[0][1] + n * 1024];
      bb1.u2[0] = *(const uint2*)&Ys[ysb[1][0] + n * 1024];
      bb1.u2[1] = *(const uint2*)&Ys[ysb[1][1] + n * 1024];
      oacc0[n] = __builtin_amdgcn_mfma_f32_16x16x32_bf16(p00.v, bb0.v, oacc0[n], 0, 0, 0);
      oacc1[n] = __builtin_amdgcn_mfma_f32_16x16x32_bf16(p01.v, bb0.v, oacc1[n], 0, 0, 0);
      oacc0[n] = __builtin_amdgcn_mfma_f32_16x16x32_bf16(p10.v, bb1.v, oacc0[n], 0, 0, 0);
      oacc1[n] = __builtin_amdgcn_mfma_f32_16x16x32_bf16(p11.v, bb1.v, oacc1[n], 0, 0, 0);
    }
    __builtin_amdgcn_s_setprio(0);
    ++ybuf; if (ybuf == 3) ybuf = 0;
  }

  // epilogue: oacc -> bf16 via LDS, coalesced store. Waves 0-3 -> XjB (rows
  // 0-127), waves 4-7 -> YsB (rows 128-255).
  __syncthreads();
  unsigned short* sb = (wv < 4) ? &XjB[0][0] : &YsB[0][0];
  const int rb = (wv & 3) * 32;
#pragma unroll
  for (int m = 0; m < 2; ++m)
#pragma unroll
    for (int n = 0; n < 8; ++n)
#pragma unroll
      for (int r = 0; r < 4; ++r) {
        int row = rb + m * 16 + g * 4 + r;
        int col = n * 16 + l15;
        sb[row * 128 + col] = f2bf(m == 0 ? oacc0[n][r] : oacc1[n][r]);
      }
  __syncthreads();
  for (int c = tid; c < 4096; c += 512) {
    int row = c >> 4, gq = c & 15;
    const unsigned short* src = (row < 128) ? &XjB[0][row * 128 + gq * 8]
                                            : &YsB[0][(row - 128) * 128 + gq * 8];
    *(uint4*)&opart[((size_t)zc * (BN * NN) + b * NN + i0 + row) * DD + gq * 8] =
        *(const uint4*)src;
  }
}

// ---- kernel 5 (MFMA): out = tanh((sum_zc opart) @ W^T + bias) + x ----
__global__ __launch_bounds__(256) void k_final(const unsigned short* __restrict__ opart,
                                               int jc,
                                               const float* __restrict__ W,
                                               const float* __restrict__ bias,
                                               const float* __restrict__ x,
                                               float* __restrict__ out) {
  __shared__ unsigned short Wb[128 * 128];    // 32 KB bf16, swizzled
  __shared__ unsigned short PreS[32 * 128];   // 8 KB bf16, swizzled
  const int tid = threadIdx.x, lane = tid & 63, wv = tid >> 6;
  const int g = lane >> 4;
  const int r0 = blockIdx.x * 32;

  {
    int h = tid >> 1, k0h = (tid & 1) * 8;
    const float* wr = W + h * 128 + k0h * 8;
#pragma unroll
    for (int q = 0; q < 8; ++q) {
      float4 v0 = *(const float4*)(wr + q * 8);
      float4 v1 = *(const float4*)(wr + q * 8 + 4);
      uint4 o;
      o.x = cvtpk(v0.x, v0.y); o.y = cvtpk(v0.z, v0.w);
      o.z = cvtpk(v1.x, v1.y); o.w = cvtpk(v1.z, v1.w);
      int gq = k0h + q;
      *(uint4*)&Wb[h * 128 + ((gq ^ (h & 7)) << 3)] = o;
    }
  }
  for (int c = tid; c < 512; c += 256) {
    int row = c >> 4, gq = c & 15;
    float s[8] = {0.f, 0.f, 0.f, 0.f, 0.f, 0.f, 0.f, 0.f};
    for (int ch = 0; ch < jc; ++ch) {
      uint4 pk = *(const uint4*)&opart[((size_t)ch * (BN * NN) + r0 + row) * DD + gq * 8];
      alignas(16) unsigned short us[8];
      *(uint4*)us = pk;
#pragma unroll
      for (int u = 0; u < 8; ++u) s[u] += bf2f(us[u]);
    }
    uint4 o;
    o.x = cvtpk(s[0], s[1]); o.y = cvtpk(s[2], s[3]);
    o.z = cvtpk(s[4], s[5]); o.w = cvtpk(s[6], s[7]);
    *(uint4*)&PreS[row * 128 + ((gq ^ (row & 7)) << 3)] = o;
  }
  __syncthreads();

  bf16x8 af[2][4], bf[2][4];
#pragma unroll
  for (int m = 0; m < 2; ++m)
#pragma unroll
    for (int kk = 0; kk < 4; ++kk) {
      int row = m * 16 + (lane & 15);
      af[m][kk] = *(const bf16x8*)&PreS[row * 128 + (((kk * 4 + g) ^ (row & 7)) << 3)];
    }
#pragma unroll
  for (int n = 0; n < 2; ++n)
#pragma unroll
    for (int kk = 0; kk < 4; ++kk) {
      int h = wv * 32 + n * 16 + (lane & 15);
      bf[n][kk] = *(const bf16x8*)&Wb[h * 128 + (((kk * 4 + g) ^ (h & 7)) << 3)];
    }

  f32x4 acc[2][2] = {};
#pragma unroll
  for (int kk = 0; kk < 4; ++kk) {
    acc[0][0] = __builtin_amdgcn_mfma_f32_16x16x32_bf16(af[0][kk], bf[0][kk], acc[0][0], 0, 0, 0);
    acc[0][1] = __builtin_amdgcn_mfma_f32_16x16x32_bf16(af[0][kk], bf[1][kk], acc[0][1], 0, 0, 0);
    acc[1][0] = __builtin_amdgcn_mfma_f32_16x16x32_bf16(af[1][kk], bf[0][kk], acc[1][0], 0, 0, 0);
    acc[1][1] = __builtin_amdgcn_mfma_f32_16x16x32_bf16(af[1][kk], bf[1][kk], acc[1][1], 0, 0, 0);
  }

  float bh0 = bias[wv * 32 + (lane & 15)];
  float bh1 = bias[wv * 32 + 16 + (lane & 15)];
#pragma unroll
  for (int m = 0; m < 2; ++m)
#pragma unroll
    for (int n = 0; n < 2; ++n)
#pragma unroll
      for (int r = 0; r < 4; ++r) {
        int row = r0 + m * 16 + g * 4 + r;
        int h = wv * 32 + n * 16 + (lane & 15);
        size_t idx = (size_t)row * 128 + h;
        out[idx] = tanhf(acc[m][n][r] + (n == 0 ? bh0 : bh1)) + x[idx];
      }
}

extern "C" void kernel_launch(void* const* d_in, const int* in_sizes, int n_in,
                              void* d_out, int out_size, void* d_ws, size_t ws_size,
                              hipStream_t stream) {
  (void)in_sizes; (void)n_in; (void)out_size;
  const float* x = (const float*)d_in[0];
  const float* W = (const float*)d_in[1];
  const float* bias = (const float*)d_in[2];
  float* out = (float*)d_out;
  char* ws = (char*)d_ws;
  unsigned short* xb = (unsigned short*)ws;                       // 4 MB @ 0
  unsigned short* yt = (unsigned short*)(ws + (4u << 20));        // 4 MB @ 4M
  float* colpart = (float*)(ws + (8u << 20));                     // 512 KB @ 8M
  unsigned short* opart = (unsigned short*)(ws + (9u << 20));     // jc*4 MB @ 9M

  // jc=8: pass2 grid = 16*4*8 = 512 = exactly 2 blocks/CU at 80 KB LDS
  const size_t need8 = (9u << 20) + 8u * (4u << 20);
  const size_t need4 = (9u << 20) + 4u * (4u << 20);
  const int jc = (ws_size >= need8) ? 8 : (ws_size >= need4) ? 4 : 1;

  k_cvt<<<1024, 256, 0, stream>>>(x, xb);
  k_colsum<<<dim3(32, 4, 8), 256, 0, stream>>>(xb, colpart);
  k_ytrans<<<dim3(2, 64, 4), 256, 0, stream>>>(x, colpart, yt);
  k_pass2<<<dim3(16, 4, jc), 512, 0, stream>>>(xb, yt, opart, jc);
  k_final<<<512, 256, 0, stream>>>(opart, jc, W, bias, x, out);
}

// Round 16
// 83.949 us; speedup vs baseline: 1.4179x; 1.4179x over previous
//
#include <hip/hip_runtime.h>
#include <hip/hip_bf16.h>

#define BN 4
#define NN 4096
#define DD 128

typedef __attribute__((ext_vector_type(8))) __bf16 bf16x8;
typedef __attribute__((ext_vector_type(4))) float f32x4;

typedef union {
  bf16x8 v;
  unsigned int u[4];
  uint2 u2[2];
} pk8;

typedef __attribute__((address_space(1))) const unsigned int* gas_p;
typedef __attribute__((address_space(3))) unsigned int* las_p;

__device__ __forceinline__ void gload16(const void* g, void* l) {
  __builtin_amdgcn_global_load_lds((gas_p)g, (las_p)l, 16, 0, 0);
}
__device__ __forceinline__ void wait_vm0() {
  asm volatile("s_waitcnt vmcnt(0)" ::: "memory");
}
__device__ __forceinline__ void wait_vm4() {
  asm volatile("s_waitcnt vmcnt(4)" ::: "memory");
}
__device__ __forceinline__ unsigned int cvtpk(float lo, float hi) {
  unsigned int r;
  asm("v_cvt_pk_bf16_f32 %0, %1, %2" : "=v"(r) : "v"(lo), "v"(hi));
  return r;
}
__device__ __forceinline__ unsigned int pkrelu(float lo, float hi) {
  return cvtpk(fmaxf(lo, 0.f), fmaxf(hi, 0.f));
}

__device__ inline unsigned short f2bf(float f) {
  unsigned int u = __float_as_uint(f);
  unsigned int r = (u + 0x7FFFu + ((u >> 16) & 1u)) >> 16;
  return (unsigned short)r;
}
__device__ inline float bf2f(unsigned short s) {
  return __uint_as_float(((unsigned int)s) << 16);
}

// ---------------- kernel 1: cast x (fp32) -> xb (bf16) ----------------
__global__ __launch_bounds__(256) void k_cvt(const float* __restrict__ x,
                                             unsigned short* __restrict__ xb) {
  int i = (blockIdx.x * 256 + threadIdx.x) * 8;
  float4 a = *(const float4*)(x + i);
  float4 c = *(const float4*)(x + i + 4);
  uint4 o;
  o.x = cvtpk(a.x, a.y);
  o.y = cvtpk(a.z, a.w);
  o.z = cvtpk(c.x, c.y);
  o.w = cvtpk(c.z, c.w);
  *(uint4*)(xb + i) = o;
}

// ---- kernel 2: colpart[(ic*BN+b)][j] = sum_{i in chunk ic} relu(<x_i,x_j>) ----
// (round-12 proven version: LDS dbuf via global_load_lds, 4 blocks/CU)
__global__ __launch_bounds__(256, 4) void k_colsum(const unsigned short* __restrict__ xb,
                                                   float* __restrict__ colpart) {
  __shared__ unsigned short XiB[2][64 * 128];  // 32 KB
  const int b = blockIdx.y, j0 = blockIdx.x * 128, ic = blockIdx.z;
  const int tid = threadIdx.x, lane = tid & 63, wv = tid >> 6;
  const unsigned short* xbb = xb + b * NN * DD;
  const int g = lane >> 4;
  const int ibeg = ic * (NN / 8);
  const int nt = (NN / 8) / 64;  // 8

#pragma unroll
  for (int hb = 0; hb < 2; ++hb)
#pragma unroll
    for (int q = 0; q < 4; ++q) {
      int c = wv * 4 + q;
      int lr = c * 4 + g;
      int gsrc = (lane & 15) ^ (lr & 7);
      gload16(&xbb[(j0 + hb * 64 + lr) * 128 + gsrc * 8], &XiB[hb][c * 512]);
    }
  wait_vm0();
  __syncthreads();

  bf16x8 bfr[2][4];
#pragma unroll
  for (int ni = 0; ni < 2; ++ni)
#pragma unroll
    for (int kk = 0; kk < 4; ++kk) {
      int lr = (wv & 1) * 32 + ni * 16 + (lane & 15);
      bfr[ni][kk] = *(const bf16x8*)&XiB[wv >> 1][lr * 128 + (((kk * 4 + g) ^ (lr & 7)) << 3)];
    }
  __syncthreads();

#pragma unroll
  for (int q = 0; q < 4; ++q) {
    int c = wv * 4 + q;
    int lr = c * 4 + g;
    int gsrc = (lane & 15) ^ (lr & 7);
    gload16(&xbb[(ibeg + lr) * 128 + gsrc * 8], &XiB[1][c * 512]);
  }

  int basek[4];
#pragma unroll
  for (int kk = 0; kk < 4; ++kk)
    basek[kk] = (lane & 15) * 128 + (((kk * 4 + g) ^ (lane & 7)) << 3);

  float colacc0 = 0.f, colacc1 = 0.f;
  for (int t = 0; t < nt; ++t) {
    wait_vm0();
    __syncthreads();
    const int cur = (t + 1) & 1, nxt = t & 1;
    if (t + 1 < nt) {
      const int i1 = ibeg + (t + 1) * 64;
#pragma unroll
      for (int q = 0; q < 4; ++q) {
        int c = wv * 4 + q;
        int lr = c * 4 + g;
        int gsrc = (lane & 15) ^ (lr & 7);
        gload16(&xbb[(i1 + lr) * 128 + gsrc * 8], &XiB[nxt][c * 512]);
      }
    }
    f32x4 a0[4], a1[4];
#pragma unroll
    for (int mj = 0; mj < 4; ++mj) { a0[mj] = (f32x4){}; a1[mj] = (f32x4){}; }
    __builtin_amdgcn_s_setprio(1);
#pragma unroll
    for (int kk = 0; kk < 4; ++kk) {
      bf16x8 ar0 = *(const bf16x8*)&XiB[cur][basek[kk]];
      bf16x8 ar1 = *(const bf16x8*)&XiB[cur][basek[kk] + 1 * 2048];
      bf16x8 ar2 = *(const bf16x8*)&XiB[cur][basek[kk] + 2 * 2048];
      bf16x8 ar3 = *(const bf16x8*)&XiB[cur][basek[kk] + 3 * 2048];
      a0[0] = __builtin_amdgcn_mfma_f32_16x16x32_bf16(ar0, bfr[0][kk], a0[0], 0, 0, 0);
      a1[0] = __builtin_amdgcn_mfma_f32_16x16x32_bf16(ar0, bfr[1][kk], a1[0], 0, 0, 0);
      a0[1] = __builtin_amdgcn_mfma_f32_16x16x32_bf16(ar1, bfr[0][kk], a0[1], 0, 0, 0);
      a1[1] = __builtin_amdgcn_mfma_f32_16x16x32_bf16(ar1, bfr[1][kk], a1[1], 0, 0, 0);
      a0[2] = __builtin_amdgcn_mfma_f32_16x16x32_bf16(ar2, bfr[0][kk], a0[2], 0, 0, 0);
      a1[2] = __builtin_amdgcn_mfma_f32_16x16x32_bf16(ar2, bfr[1][kk], a1[2], 0, 0, 0);
      a0[3] = __builtin_amdgcn_mfma_f32_16x16x32_bf16(ar3, bfr[0][kk], a0[3], 0, 0, 0);
      a1[3] = __builtin_amdgcn_mfma_f32_16x16x32_bf16(ar3, bfr[1][kk], a1[3], 0, 0, 0);
    }
    __builtin_amdgcn_s_setprio(0);
    {
      float s0 = 0.f, s1 = 0.f;
#pragma unroll
      for (int mj = 0; mj < 4; ++mj)
#pragma unroll
        for (int r = 0; r < 4; ++r) {
          s0 += fmaxf(a0[mj][r], 0.f);
          s1 += fmaxf(a1[mj][r], 0.f);
        }
      s0 += __shfl_xor(s0, 16); s0 += __shfl_xor(s0, 32);
      s1 += __shfl_xor(s1, 16); s1 += __shfl_xor(s1, 32);
      colacc0 += s0; colacc1 += s1;
    }
  }
  if (lane < 16) {
    colpart[(ic * BN + b) * NN + j0 + wv * 32 + lane] = colacc0;
    colpart[(ic * BN + b) * NN + j0 + wv * 32 + 16 + lane] = colacc1;
  }
}

// ---- kernel 3: yt[b][d][j] = bf16(x[b][j][d] / sum_ic colpart) ----
__global__ __launch_bounds__(256) void k_ytrans(const float* __restrict__ x,
                                                const float* __restrict__ colpart,
                                                unsigned short* __restrict__ yt) {
  __shared__ unsigned short T[64 * 72];
  const int b = blockIdx.z, j0 = blockIdx.y * 64, d0 = blockIdx.x * 64;
  const int tid = threadIdx.x;
  int jr = tid >> 2, q0 = (tid & 3) * 16;
  float cs = 0.f;
#pragma unroll
  for (int ic = 0; ic < 8; ++ic) cs += colpart[(ic * BN + b) * NN + j0 + jr];
  float inv = 1.0f / cs;
  const float* xr = x + (size_t)(b * NN + j0 + jr) * DD + d0 + q0;
#pragma unroll
  for (int q = 0; q < 4; ++q) {
    float4 v = *(const float4*)(xr + q * 4);
    int dc = q0 + q * 4;
    T[jr * 72 + dc + 0] = f2bf(v.x * inv);
    T[jr * 72 + dc + 1] = f2bf(v.y * inv);
    T[jr * 72 + dc + 2] = f2bf(v.z * inv);
    T[jr * 72 + dc + 3] = f2bf(v.w * inv);
  }
  __syncthreads();
  for (int c = tid; c < 512; c += 256) {
    int dr = c >> 3, jg = c & 7;
    alignas(16) unsigned short tmp[8];
#pragma unroll
    for (int u = 0; u < 8; ++u) tmp[u] = T[(jg * 8 + u) * 72 + dr];
    *(uint4*)&yt[(size_t)(b * DD + d0 + dr) * NN + j0 + jg * 8] = *(const uint4*)tmp;
  }
}

// ---- kernel 4: opart[zc][b*NN+i][:] = sum_{j in chunk zc} relu(<x_i,x_j>) y[j][:] ----
// round-12 proven structure (Ys 3-buf, counted vmcnt(4)); epilogue sb now
// XOR-swizzled on BOTH sides to kill the 8-way ds_write_b16 bank conflict.
__global__ __launch_bounds__(256, 2) void k_pass2(const unsigned short* __restrict__ xb,
                                                  const unsigned short* __restrict__ yt,
                                                  unsigned short* __restrict__ opart,
                                                  int jc) {
  __shared__ unsigned short XjB[2][64 * 128];  // 32 KB (Xi in prologue; sb in epilogue)
  __shared__ unsigned short YsB[3][128 * 64];  // 48 KB, triple buffer
  const int b = blockIdx.y, i0 = blockIdx.x * 128, zc = blockIdx.z;
  const int tid = threadIdx.x, lane = tid & 63, wv = tid >> 6;
  const unsigned short* xbb = xb + b * NN * DD;
  const unsigned short* ytb = yt + (size_t)b * DD * NN;
  const int g = lane >> 4, l15 = lane & 15;

  const int jspan = NN / jc;
  const int jbeg = zc * jspan;
  const int nt = jspan / 64;

  // prologue: Xi 128 rows -> XjB[0] + XjB[1]
#pragma unroll
  for (int hb = 0; hb < 2; ++hb)
#pragma unroll
    for (int q = 0; q < 4; ++q) {
      int c = wv * 4 + q;
      int lr = c * 4 + g;
      int gsrc = l15 ^ (lr & 7);
      gload16(&xbb[(i0 + hb * 64 + lr) * 128 + gsrc * 8], &XjB[hb][c * 512]);
    }
  wait_vm0();
  __syncthreads();

  // Xi B-frags: wave's 32 i = wv*32 + ni*16 + l15
  bf16x8 bfr[2][4];
#pragma unroll
  for (int ni = 0; ni < 2; ++ni)
#pragma unroll
    for (int kk = 0; kk < 4; ++kk) {
      int lr = (wv & 1) * 32 + ni * 16 + l15;
      bfr[ni][kk] = *(const bf16x8*)&XjB[wv >> 1][lr * 128 + (((kk * 4 + g) ^ (lr & 7)) << 3)];
    }
  __syncthreads();  // XjB free

  // issue (oldest-first): Xj0 -> XjB[0], Ys0 -> YsB[0], Ys1 -> YsB[1]
#pragma unroll
  for (int q = 0; q < 4; ++q) {
    int c = wv * 4 + q;
    int lr = c * 4 + g;
    int gsrc = l15 ^ (lr & 7);
    gload16(&xbb[(jbeg + lr) * 128 + gsrc * 8], &XjB[0][c * 512]);
  }
#pragma unroll
  for (int q = 0; q < 4; ++q) {
    int c = wv * 4 + q;
    int dr = c * 8 + (lane >> 3);
    int gsrc = (lane & 7) ^ (dr & 7);
    gload16(&ytb[(size_t)dr * NN + jbeg + gsrc * 8], &YsB[0][c * 512]);
  }
  if (1 < nt) {
#pragma unroll
    for (int q = 0; q < 4; ++q) {
      int c = wv * 4 + q;
      int dr = c * 8 + (lane >> 3);
      int gsrc = (lane & 7) ^ (dr & 7);
      gload16(&ytb[(size_t)dr * NN + jbeg + 64 + gsrc * 8], &YsB[1][c * 512]);
    }
  }

  int xjb[4];   // S^T A-frag bases in Xj tile
#pragma unroll
  for (int kk = 0; kk < 4; ++kk)
    xjb[kk] = l15 * 128 + (((kk * 4 + g) ^ (l15 & 7)) << 3);
  int ysb[2][2];  // PV B b64 offsets (within a Ys buffer)
#pragma unroll
  for (int c = 0; c < 2; ++c)
#pragma unroll
    for (int h = 0; h < 2; ++h) {
      int jq = c * 4 + 2 * h + (g >> 1);
      ysb[c][h] = l15 * 64 + ((jq ^ (l15 & 7)) << 3) + (g & 1) * 4;
    }

  f32x4 oacc0[8], oacc1[8];
#pragma unroll
  for (int n = 0; n < 8; ++n) { oacc0[n] = (f32x4){}; oacc1[n] = (f32x4){}; }

  int ybuf = 0;  // = t % 3
  for (int t = 0; t < nt; ++t) {
    // counted wait: keep newest 4 (Ys[t+1]) in flight except at the last iter
    if (t + 1 < nt) wait_vm4(); else wait_vm0();
    __syncthreads();
    // issue next tiles (Xj[t+1] first, then Ys[t+2] — oldest-first discipline)
    if (t + 1 < nt) {
      const int j1 = jbeg + (t + 1) * 64;
#pragma unroll
      for (int q = 0; q < 4; ++q) {
        int c = wv * 4 + q;
        int lr = c * 4 + g;
        int gsrc = l15 ^ (lr & 7);
        gload16(&xbb[(j1 + lr) * 128 + gsrc * 8], &XjB[(t + 1) & 1][c * 512]);
      }
      if (t + 2 < nt) {
        const int j2 = jbeg + (t + 2) * 64;
        int nb = ybuf + 2; if (nb >= 3) nb -= 3;
#pragma unroll
        for (int q = 0; q < 4; ++q) {
          int c = wv * 4 + q;
          int dr = c * 8 + (lane >> 3);
          int gsrc = (lane & 7) ^ (dr & 7);
          gload16(&ytb[(size_t)dr * NN + j2 + gsrc * 8], &YsB[nb][c * 512]);
        }
      }
    }
    const unsigned short* Xj = XjB[t & 1];
    const unsigned short* Ys = YsB[ybuf];

    f32x4 s0[4], s1[4];
#pragma unroll
    for (int mj = 0; mj < 4; ++mj) { s0[mj] = (f32x4){}; s1[mj] = (f32x4){}; }
    __builtin_amdgcn_s_setprio(1);
#pragma unroll
    for (int kk = 0; kk < 4; ++kk) {
      bf16x8 ar0 = *(const bf16x8*)&Xj[xjb[kk]];
      bf16x8 ar1 = *(const bf16x8*)&Xj[xjb[kk] + 1 * 2048];
      bf16x8 ar2 = *(const bf16x8*)&Xj[xjb[kk] + 2 * 2048];
      bf16x8 ar3 = *(const bf16x8*)&Xj[xjb[kk] + 3 * 2048];
      s0[0] = __builtin_amdgcn_mfma_f32_16x16x32_bf16(ar0, bfr[0][kk], s0[0], 0, 0, 0);
      s1[0] = __builtin_amdgcn_mfma_f32_16x16x32_bf16(ar0, bfr[1][kk], s1[0], 0, 0, 0);
      s0[1] = __builtin_amdgcn_mfma_f32_16x16x32_bf16(ar1, bfr[0][kk], s0[1], 0, 0, 0);
      s1[1] = __builtin_amdgcn_mfma_f32_16x16x32_bf16(ar1, bfr[1][kk], s1[1], 0, 0, 0);
      s0[2] = __builtin_amdgcn_mfma_f32_16x16x32_bf16(ar2, bfr[0][kk], s0[2], 0, 0, 0);
      s1[2] = __builtin_amdgcn_mfma_f32_16x16x32_bf16(ar2, bfr[1][kk], s1[2], 0, 0, 0);
      s0[3] = __builtin_amdgcn_mfma_f32_16x16x32_bf16(ar3, bfr[0][kk], s0[3], 0, 0, 0);
      s1[3] = __builtin_amdgcn_mfma_f32_16x16x32_bf16(ar3, bfr[1][kk], s1[3], 0, 0, 0);
    }
    __builtin_amdgcn_s_setprio(0);
    pk8 p00, p01, p10, p11;
    p00.u[0] = pkrelu(s0[0][0], s0[0][1]); p00.u[1] = pkrelu(s0[0][2], s0[0][3]);
    p00.u[2] = pkrelu(s0[1][0], s0[1][1]); p00.u[3] = pkrelu(s0[1][2], s0[1][3]);
    p01.u[0] = pkrelu(s1[0][0], s1[0][1]); p01.u[1] = pkrelu(s1[0][2], s1[0][3]);
    p01.u[2] = pkrelu(s1[1][0], s1[1][1]); p01.u[3] = pkrelu(s1[1][2], s1[1][3]);
    p10.u[0] = pkrelu(s0[2][0], s0[2][1]); p10.u[1] = pkrelu(s0[2][2], s0[2][3]);
    p10.u[2] = pkrelu(s0[3][0], s0[3][1]); p10.u[3] = pkrelu(s0[3][2], s0[3][3]);
    p11.u[0] = pkrelu(s1[2][0], s1[2][1]); p11.u[1] = pkrelu(s1[2][2], s1[2][3]);
    p11.u[2] = pkrelu(s1[3][0], s1[3][1]); p11.u[3] = pkrelu(s1[3][2], s1[3][3]);
    __builtin_amdgcn_s_setprio(1);
#pragma unroll
    for (int n = 0; n < 8; ++n) {
      pk8 bb0, bb1;
      bb0.u2[0] = *(const uint2*)&Ys[ysb[0][0] + n * 1024];
      bb0.u2[1] = *(const uint2*)&Ys[ysb[0][1] + n * 1024];
      bb1.u2[0] = *(const uint2*)&Ys[ysb[1][0] + n * 1024];
      bb1.u2[1] = *(const uint2*)&Ys[ysb[1][1] + n * 1024];
      oacc0[n] = __builtin_amdgcn_mfma_f32_16x16x32_bf16(p00.v, bb0.v, oacc0[n], 0, 0, 0);
      oacc1[n] = __builtin_amdgcn_mfma_f32_16x16x32_bf16(p01.v, bb0.v, oacc1[n], 0, 0, 0);
      oacc0[n] = __builtin_amdgcn_mfma_f32_16x16x32_bf16(p10.v, bb1.v, oacc0[n], 0, 0, 0);
      oacc1[n] = __builtin_amdgcn_mfma_f32_16x16x32_bf16(p11.v, bb1.v, oacc1[n], 0, 0, 0);
    }
    __builtin_amdgcn_s_setprio(0);
    ++ybuf; if (ybuf == 3) ybuf = 0;
  }

  // epilogue: oacc -> bf16 via LDS (XjB 32 KB), XOR-swizzled both sides to
  // avoid the 8-way b16-write bank conflict; coalesced uint4 store.
  __syncthreads();
  unsigned short* sb = &XjB[0][0];  // 128 x 128 bf16 (swizzled granules)
#pragma unroll
  for (int m = 0; m < 2; ++m)
#pragma unroll
    for (int n = 0; n < 8; ++n)
#pragma unroll
      for (int r = 0; r < 4; ++r) {
        int row = wv * 32 + m * 16 + g * 4 + r;
        int col = n * 16 + l15;
        sb[row * 128 + (((col >> 3) ^ (row & 7)) << 3) + (col & 7)] =
            f2bf(m == 0 ? oacc0[n][r] : oacc1[n][r]);
      }
  __syncthreads();
  for (int c = tid; c < 2048; c += 256) {
    int row = c >> 4, gq = c & 15;
    *(uint4*)&opart[((size_t)zc * (BN * NN) + b * NN + i0 + row) * DD + gq * 8] =
        *(const uint4*)&sb[row * 128 + ((gq ^ (row & 7)) << 3)];
  }
}

// ---- kernel 5 (MFMA): out = tanh((sum_zc opart) @ W^T + bias) + x ----
__global__ __launch_bounds__(256) void k_final(const unsigned short* __restrict__ opart,
                                               int jc,
                                               const float* __restrict__ W,
                                               const float* __restrict__ bias,
                                               const float* __restrict__ x,
                                               float* __restrict__ out) {
  __shared__ unsigned short Wb[128 * 128];    // 32 KB bf16, swizzled
  __shared__ unsigned short PreS[32 * 128];   // 8 KB bf16, swizzled
  const int tid = threadIdx.x, lane = tid & 63, wv = tid >> 6;
  const int g = lane >> 4;
  const int r0 = blockIdx.x * 32;

  {
    int h = tid >> 1, k0h = (tid & 1) * 8;
    const float* wr = W + h * 128 + k0h * 8;
#pragma unroll
    for (int q = 0; q < 8; ++q) {
      float4 v0 = *(const float4*)(wr + q * 8);
      float4 v1 = *(const float4*)(wr + q * 8 + 4);
      uint4 o;
      o.x = cvtpk(v0.x, v0.y); o.y = cvtpk(v0.z, v0.w);
      o.z = cvtpk(v1.x, v1.y); o.w = cvtpk(v1.z, v1.w);
      int gq = k0h + q;
      *(uint4*)&Wb[h * 128 + ((gq ^ (h & 7)) << 3)] = o;
    }
  }
  for (int c = tid; c < 512; c += 256) {
    int row = c >> 4, gq = c & 15;
    float s[8] = {0.f, 0.f, 0.f, 0.f, 0.f, 0.f, 0.f, 0.f};
    for (int ch = 0; ch < jc; ++ch) {
      uint4 pk = *(const uint4*)&opart[((size_t)ch * (BN * NN) + r0 + row) * DD + gq * 8];
      alignas(16) unsigned short us[8];
      *(uint4*)us = pk;
#pragma unroll
      for (int u = 0; u < 8; ++u) s[u] += bf2f(us[u]);
    }
    uint4 o;
    o.x = cvtpk(s[0], s[1]); o.y = cvtpk(s[2], s[3]);
    o.z = cvtpk(s[4], s[5]); o.w = cvtpk(s[6], s[7]);
    *(uint4*)&PreS[row * 128 + ((gq ^ (row & 7)) << 3)] = o;
  }
  __syncthreads();

  bf16x8 af[2][4], bf[2][4];
#pragma unroll
  for (int m = 0; m < 2; ++m)
#pragma unroll
    for (int kk = 0; kk < 4; ++kk) {
      int row = m * 16 + (lane & 15);
      af[m][kk] = *(const bf16x8*)&PreS[row * 128 + (((kk * 4 + g) ^ (row & 7)) << 3)];
    }
#pragma unroll
  for (int n = 0; n < 2; ++n)
#pragma unroll
    for (int kk = 0; kk < 4; ++kk) {
      int h = wv * 32 + n * 16 + (lane & 15);
      bf[n][kk] = *(const bf16x8*)&Wb[h * 128 + (((kk * 4 + g) ^ (h & 7)) << 3)];
    }

  f32x4 acc[2][2] = {};
#pragma unroll
  for (int kk = 0; kk < 4; ++kk) {
    acc[0][0] = __builtin_amdgcn_mfma_f32_16x16x32_bf16(af[0][kk], bf[0][kk], acc[0][0], 0, 0, 0);
    acc[0][1] = __builtin_amdgcn_mfma_f32_16x16x32_bf16(af[0][kk], bf[1][kk], acc[0][1], 0, 0, 0);
    acc[1][0] = __builtin_amdgcn_mfma_f32_16x16x32_bf16(af[1][kk], bf[0][kk], acc[1][0], 0, 0, 0);
    acc[1][1] = __builtin_amdgcn_mfma_f32_16x16x32_bf16(af[1][kk], bf[1][kk], acc[1][1], 0, 0, 0);
  }

  float bh0 = bias[wv * 32 + (lane & 15)];
  float bh1 = bias[wv * 32 + 16 + (lane & 15)];
#pragma unroll
  for (int m = 0; m < 2; ++m)
#pragma unroll
    for (int n = 0; n < 2; ++n)
#pragma unroll
      for (int r = 0; r < 4; ++r) {
        int row = r0 + m * 16 + g * 4 + r;
        int h = wv * 32 + n * 16 + (lane & 15);
        size_t idx = (size_t)row * 128 + h;
        out[idx] = tanhf(acc[m][n][r] + (n == 0 ? bh0 : bh1)) + x[idx];
      }
}

extern "C" void kernel_launch(void* const* d_in, const int* in_sizes, int n_in,
                              void* d_out, int out_size, void* d_ws, size_t ws_size,
                              hipStream_t stream) {
  (void)in_sizes; (void)n_in; (void)out_size;
  const float* x = (const float*)d_in[0];
  const float* W = (const float*)d_in[1];
  const float* bias = (const float*)d_in[2];
  float* out = (float*)d_out;
  char* ws = (char*)d_ws;
  unsigned short* xb = (unsigned short*)ws;                       // 4 MB @ 0
  unsigned short* yt = (unsigned short*)(ws + (4u << 20));        // 4 MB @ 4M
  float* colpart = (float*)(ws + (8u << 20));                     // 512 KB @ 8M
  unsigned short* opart = (unsigned short*)(ws + (9u << 20));     // jc*4 MB @ 9M

  const size_t need4 = (9u << 20) + 4u * (4u << 20);
  const int jc = (ws_size >= need4) ? 4 : 1;

  k_cvt<<<1024, 256, 0, stream>>>(x, xb);
  k_colsum<<<dim3(32, 4, 8), 256, 0, stream>>>(xb, colpart);
  k_ytrans<<<dim3(2, 64, 4), 256, 0, stream>>>(x, colpart, yt);
  k_pass2<<<dim3(32, 4, jc), 256, 0, stream>>>(xb, yt, opart, jc);
  k_final<<<512, 256, 0, stream>>>(opart, jc, W, bias, x, out);
}

// Round 17
// 81.719 us; speedup vs baseline: 1.4566x; 1.0273x over previous
//
#include <hip/hip_runtime.h>
#include <hip/hip_bf16.h>

#define BN 4
#define NN 4096
#define DD 128

typedef __attribute__((ext_vector_type(8))) __bf16 bf16x8;
typedef __attribute__((ext_vector_type(4))) float f32x4;

typedef union {
  bf16x8 v;
  unsigned int u[4];
  uint2 u2[2];
} pk8;

typedef __attribute__((address_space(1))) const unsigned int* gas_p;
typedef __attribute__((address_space(3))) unsigned int* las_p;

__device__ __forceinline__ void gload16(const void* g, void* l) {
  __builtin_amdgcn_global_load_lds((gas_p)g, (las_p)l, 16, 0, 0);
}
__device__ __forceinline__ void wait_vm0() {
  asm volatile("s_waitcnt vmcnt(0)" ::: "memory");
}
__device__ __forceinline__ void wait_vm4() {
  asm volatile("s_waitcnt vmcnt(4)" ::: "memory");
}
__device__ __forceinline__ unsigned int cvtpk(float lo, float hi) {
  unsigned int r;
  asm("v_cvt_pk_bf16_f32 %0, %1, %2" : "=v"(r) : "v"(lo), "v"(hi));
  return r;
}
__device__ __forceinline__ unsigned int pkrelu(float lo, float hi) {
  return cvtpk(fmaxf(lo, 0.f), fmaxf(hi, 0.f));
}

__device__ inline unsigned short f2bf(float f) {
  unsigned int u = __float_as_uint(f);
  unsigned int r = (u + 0x7FFFu + ((u >> 16) & 1u)) >> 16;
  return (unsigned short)r;
}
__device__ inline float bf2f(unsigned short s) {
  return __uint_as_float(((unsigned int)s) << 16);
}

// ---------------- kernel 1: cast x (fp32) -> xb (bf16) ----------------
__global__ __launch_bounds__(256) void k_cvt(const float* __restrict__ x,
                                             unsigned short* __restrict__ xb) {
  int i = (blockIdx.x * 256 + threadIdx.x) * 8;
  float4 a = *(const float4*)(x + i);
  float4 c = *(const float4*)(x + i + 4);
  uint4 o;
  o.x = cvtpk(a.x, a.y);
  o.y = cvtpk(a.z, a.w);
  o.z = cvtpk(c.x, c.y);
  o.w = cvtpk(c.z, c.w);
  *(uint4*)(xb + i) = o;
}

// ---- kernel 2: colpart[(ic*BN+b)][j] = sum_{i in chunk ic} relu(<x_i,x_j>) ----
// (round-12 proven version: LDS dbuf via global_load_lds, 4 blocks/CU)
__global__ __launch_bounds__(256, 4) void k_colsum(const unsigned short* __restrict__ xb,
                                                   float* __restrict__ colpart) {
  __shared__ unsigned short XiB[2][64 * 128];  // 32 KB
  const int b = blockIdx.y, j0 = blockIdx.x * 128, ic = blockIdx.z;
  const int tid = threadIdx.x, lane = tid & 63, wv = tid >> 6;
  const unsigned short* xbb = xb + b * NN * DD;
  const int g = lane >> 4;
  const int ibeg = ic * (NN / 8);
  const int nt = (NN / 8) / 64;  // 8

#pragma unroll
  for (int hb = 0; hb < 2; ++hb)
#pragma unroll
    for (int q = 0; q < 4; ++q) {
      int c = wv * 4 + q;
      int lr = c * 4 + g;
      int gsrc = (lane & 15) ^ (lr & 7);
      gload16(&xbb[(j0 + hb * 64 + lr) * 128 + gsrc * 8], &XiB[hb][c * 512]);
    }
  wait_vm0();
  __syncthreads();

  bf16x8 bfr[2][4];
#pragma unroll
  for (int ni = 0; ni < 2; ++ni)
#pragma unroll
    for (int kk = 0; kk < 4; ++kk) {
      int lr = (wv & 1) * 32 + ni * 16 + (lane & 15);
      bfr[ni][kk] = *(const bf16x8*)&XiB[wv >> 1][lr * 128 + (((kk * 4 + g) ^ (lr & 7)) << 3)];
    }
  __syncthreads();

#pragma unroll
  for (int q = 0; q < 4; ++q) {
    int c = wv * 4 + q;
    int lr = c * 4 + g;
    int gsrc = (lane & 15) ^ (lr & 7);
    gload16(&xbb[(ibeg + lr) * 128 + gsrc * 8], &XiB[1][c * 512]);
  }

  int basek[4];
#pragma unroll
  for (int kk = 0; kk < 4; ++kk)
    basek[kk] = (lane & 15) * 128 + (((kk * 4 + g) ^ (lane & 7)) << 3);

  float colacc0 = 0.f, colacc1 = 0.f;
  for (int t = 0; t < nt; ++t) {
    wait_vm0();
    __syncthreads();
    const int cur = (t + 1) & 1, nxt = t & 1;
    if (t + 1 < nt) {
      const int i1 = ibeg + (t + 1) * 64;
#pragma unroll
      for (int q = 0; q < 4; ++q) {
        int c = wv * 4 + q;
        int lr = c * 4 + g;
        int gsrc = (lane & 15) ^ (lr & 7);
        gload16(&xbb[(i1 + lr) * 128 + gsrc * 8], &XiB[nxt][c * 512]);
      }
    }
    f32x4 a0[4], a1[4];
#pragma unroll
    for (int mj = 0; mj < 4; ++mj) { a0[mj] = (f32x4){}; a1[mj] = (f32x4){}; }
    __builtin_amdgcn_s_setprio(1);
#pragma unroll
    for (int kk = 0; kk < 4; ++kk) {
      bf16x8 ar0 = *(const bf16x8*)&XiB[cur][basek[kk]];
      bf16x8 ar1 = *(const bf16x8*)&XiB[cur][basek[kk] + 1 * 2048];
      bf16x8 ar2 = *(const bf16x8*)&XiB[cur][basek[kk] + 2 * 2048];
      bf16x8 ar3 = *(const bf16x8*)&XiB[cur][basek[kk] + 3 * 2048];
      a0[0] = __builtin_amdgcn_mfma_f32_16x16x32_bf16(ar0, bfr[0][kk], a0[0], 0, 0, 0);
      a1[0] = __builtin_amdgcn_mfma_f32_16x16x32_bf16(ar0, bfr[1][kk], a1[0], 0, 0, 0);
      a0[1] = __builtin_amdgcn_mfma_f32_16x16x32_bf16(ar1, bfr[0][kk], a0[1], 0, 0, 0);
      a1[1] = __builtin_amdgcn_mfma_f32_16x16x32_bf16(ar1, bfr[1][kk], a1[1], 0, 0, 0);
      a0[2] = __builtin_amdgcn_mfma_f32_16x16x32_bf16(ar2, bfr[0][kk], a0[2], 0, 0, 0);
      a1[2] = __builtin_amdgcn_mfma_f32_16x16x32_bf16(ar2, bfr[1][kk], a1[2], 0, 0, 0);
      a0[3] = __builtin_amdgcn_mfma_f32_16x16x32_bf16(ar3, bfr[0][kk], a0[3], 0, 0, 0);
      a1[3] = __builtin_amdgcn_mfma_f32_16x16x32_bf16(ar3, bfr[1][kk], a1[3], 0, 0, 0);
    }
    __builtin_amdgcn_s_setprio(0);
    {
      float s0 = 0.f, s1 = 0.f;
#pragma unroll
      for (int mj = 0; mj < 4; ++mj)
#pragma unroll
        for (int r = 0; r < 4; ++r) {
          s0 += fmaxf(a0[mj][r], 0.f);
          s1 += fmaxf(a1[mj][r], 0.f);
        }
      s0 += __shfl_xor(s0, 16); s0 += __shfl_xor(s0, 32);
      s1 += __shfl_xor(s1, 16); s1 += __shfl_xor(s1, 32);
      colacc0 += s0; colacc1 += s1;
    }
  }
  if (lane < 16) {
    colpart[(ic * BN + b) * NN + j0 + wv * 32 + lane] = colacc0;
    colpart[(ic * BN + b) * NN + j0 + wv * 32 + 16 + lane] = colacc1;
  }
}

// ---- kernel 3: yt[b][d][jp] = bf16(x[b][perm(jp)][d] / colsum) ----
// j-order within each aligned 64-block is PERMUTED to pass2's PV k-map:
// position p = G*8+e holds j = (G>>2)*32 + (G&3)*4 + (e&3) + (e>>2)*16,
// so pass2 can read one b128 per MFMA B-operand.
__global__ __launch_bounds__(256) void k_ytrans(const float* __restrict__ x,
                                                const float* __restrict__ colpart,
                                                unsigned short* __restrict__ yt) {
  __shared__ unsigned short T[64 * 72];
  const int b = blockIdx.z, j0 = blockIdx.y * 64, d0 = blockIdx.x * 64;
  const int tid = threadIdx.x;
  int jr = tid >> 2, q0 = (tid & 3) * 16;
  float cs = 0.f;
#pragma unroll
  for (int ic = 0; ic < 8; ++ic) cs += colpart[(ic * BN + b) * NN + j0 + jr];
  float inv = 1.0f / cs;
  const float* xr = x + (size_t)(b * NN + j0 + jr) * DD + d0 + q0;
#pragma unroll
  for (int q = 0; q < 4; ++q) {
    float4 v = *(const float4*)(xr + q * 4);
    int dc = q0 + q * 4;
    T[jr * 72 + dc + 0] = f2bf(v.x * inv);
    T[jr * 72 + dc + 1] = f2bf(v.y * inv);
    T[jr * 72 + dc + 2] = f2bf(v.z * inv);
    T[jr * 72 + dc + 3] = f2bf(v.w * inv);
  }
  __syncthreads();
  for (int c = tid; c < 512; c += 256) {
    int dr = c >> 3, jg = c & 7;
    alignas(16) unsigned short tmp[8];
#pragma unroll
    for (int u = 0; u < 8; ++u) {
      int jj = (jg >> 2) * 32 + (jg & 3) * 4 + (u & 3) + (u >> 2) * 16;
      tmp[u] = T[jj * 72 + dr];
    }
    *(uint4*)&yt[(size_t)(b * DD + d0 + dr) * NN + j0 + jg * 8] = *(const uint4*)tmp;
  }
}

// ---- kernel 4: opart[zc][b*NN+i][:] = sum_{j in chunk zc} relu(<x_i,x_j>) y[j][:] ----
// round-12 structure; PV B-operand = single ds_read_b128 per MFMA thanks to
// the yt j-permutation (S-phase-style clean bank pattern, half the reads).
__global__ __launch_bounds__(256, 2) void k_pass2(const unsigned short* __restrict__ xb,
                                                  const unsigned short* __restrict__ yt,
                                                  unsigned short* __restrict__ opart,
                                                  int jc) {
  __shared__ unsigned short XjB[2][64 * 128];  // 32 KB (Xi in prologue; sb in epilogue)
  __shared__ unsigned short YsB[3][128 * 64];  // 48 KB, triple buffer
  const int b = blockIdx.y, i0 = blockIdx.x * 128, zc = blockIdx.z;
  const int tid = threadIdx.x, lane = tid & 63, wv = tid >> 6;
  const unsigned short* xbb = xb + b * NN * DD;
  const unsigned short* ytb = yt + (size_t)b * DD * NN;
  const int g = lane >> 4, l15 = lane & 15;

  const int jspan = NN / jc;
  const int jbeg = zc * jspan;
  const int nt = jspan / 64;

  // prologue: Xi 128 rows -> XjB[0] + XjB[1]
#pragma unroll
  for (int hb = 0; hb < 2; ++hb)
#pragma unroll
    for (int q = 0; q < 4; ++q) {
      int c = wv * 4 + q;
      int lr = c * 4 + g;
      int gsrc = l15 ^ (lr & 7);
      gload16(&xbb[(i0 + hb * 64 + lr) * 128 + gsrc * 8], &XjB[hb][c * 512]);
    }
  wait_vm0();
  __syncthreads();

  // Xi B-frags: wave's 32 i = wv*32 + ni*16 + l15
  bf16x8 bfr[2][4];
#pragma unroll
  for (int ni = 0; ni < 2; ++ni)
#pragma unroll
    for (int kk = 0; kk < 4; ++kk) {
      int lr = (wv & 1) * 32 + ni * 16 + l15;
      bfr[ni][kk] = *(const bf16x8*)&XjB[wv >> 1][lr * 128 + (((kk * 4 + g) ^ (lr & 7)) << 3)];
    }
  __syncthreads();  // XjB free

  // issue (oldest-first): Xj0 -> XjB[0], Ys0 -> YsB[0], Ys1 -> YsB[1]
#pragma unroll
  for (int q = 0; q < 4; ++q) {
    int c = wv * 4 + q;
    int lr = c * 4 + g;
    int gsrc = l15 ^ (lr & 7);
    gload16(&xbb[(jbeg + lr) * 128 + gsrc * 8], &XjB[0][c * 512]);
  }
#pragma unroll
  for (int q = 0; q < 4; ++q) {
    int c = wv * 4 + q;
    int dr = c * 8 + (lane >> 3);
    int gsrc = (lane & 7) ^ (dr & 7);
    gload16(&ytb[(size_t)dr * NN + jbeg + gsrc * 8], &YsB[0][c * 512]);
  }
  if (1 < nt) {
#pragma unroll
    for (int q = 0; q < 4; ++q) {
      int c = wv * 4 + q;
      int dr = c * 8 + (lane >> 3);
      int gsrc = (lane & 7) ^ (dr & 7);
      gload16(&ytb[(size_t)dr * NN + jbeg + 64 + gsrc * 8], &YsB[1][c * 512]);
    }
  }

  int xjb[4];   // S^T A-frag bases in Xj tile
#pragma unroll
  for (int kk = 0; kk < 4; ++kk)
    xjb[kk] = l15 * 128 + (((kk * 4 + g) ^ (l15 & 7)) << 3);
  int ysb[2];   // PV B b128 bases: granule G = c*4+g, row-xor swizzled
#pragma unroll
  for (int c = 0; c < 2; ++c)
    ysb[c] = l15 * 64 + (((c * 4 + g) ^ (l15 & 7)) << 3);

  f32x4 oacc0[8], oacc1[8];
#pragma unroll
  for (int n = 0; n < 8; ++n) { oacc0[n] = (f32x4){}; oacc1[n] = (f32x4){}; }

  int ybuf = 0;  // = t % 3
  for (int t = 0; t < nt; ++t) {
    // counted wait: keep newest 4 (Ys[t+1]) in flight except at the last iter
    if (t + 1 < nt) wait_vm4(); else wait_vm0();
    __syncthreads();
    // issue next tiles (Xj[t+1] first, then Ys[t+2] — oldest-first discipline)
    if (t + 1 < nt) {
      const int j1 = jbeg + (t + 1) * 64;
#pragma unroll
      for (int q = 0; q < 4; ++q) {
        int c = wv * 4 + q;
        int lr = c * 4 + g;
        int gsrc = l15 ^ (lr & 7);
        gload16(&xbb[(j1 + lr) * 128 + gsrc * 8], &XjB[(t + 1) & 1][c * 512]);
      }
      if (t + 2 < nt) {
        const int j2 = jbeg + (t + 2) * 64;
        int nb = ybuf + 2; if (nb >= 3) nb -= 3;
#pragma unroll
        for (int q = 0; q < 4; ++q) {
          int c = wv * 4 + q;
          int dr = c * 8 + (lane >> 3);
          int gsrc = (lane & 7) ^ (dr & 7);
          gload16(&ytb[(size_t)dr * NN + j2 + gsrc * 8], &YsB[nb][c * 512]);
        }
      }
    }
    const unsigned short* Xj = XjB[t & 1];
    const unsigned short* Ys = YsB[ybuf];

    f32x4 s0[4], s1[4];
#pragma unroll
    for (int mj = 0; mj < 4; ++mj) { s0[mj] = (f32x4){}; s1[mj] = (f32x4){}; }
    __builtin_amdgcn_s_setprio(1);
#pragma unroll
    for (int kk = 0; kk < 4; ++kk) {
      bf16x8 ar0 = *(const bf16x8*)&Xj[xjb[kk]];
      bf16x8 ar1 = *(const bf16x8*)&Xj[xjb[kk] + 1 * 2048];
      bf16x8 ar2 = *(const bf16x8*)&Xj[xjb[kk] + 2 * 2048];
      bf16x8 ar3 = *(const bf16x8*)&Xj[xjb[kk] + 3 * 2048];
      s0[0] = __builtin_amdgcn_mfma_f32_16x16x32_bf16(ar0, bfr[0][kk], s0[0], 0, 0, 0);
      s1[0] = __builtin_amdgcn_mfma_f32_16x16x32_bf16(ar0, bfr[1][kk], s1[0], 0, 0, 0);
      s0[1] = __builtin_amdgcn_mfma_f32_16x16x32_bf16(ar1, bfr[0][kk], s0[1], 0, 0, 0);
      s1[1] = __builtin_amdgcn_mfma_f32_16x16x32_bf16(ar1, bfr[1][kk], s1[1], 0, 0, 0);
      s0[2] = __builtin_amdgcn_mfma_f32_16x16x32_bf16(ar2, bfr[0][kk], s0[2], 0, 0, 0);
      s1[2] = __builtin_amdgcn_mfma_f32_16x16x32_bf16(ar2, bfr[1][kk], s1[2], 0, 0, 0);
      s0[3] = __builtin_amdgcn_mfma_f32_16x16x32_bf16(ar3, bfr[0][kk], s0[3], 0, 0, 0);
      s1[3] = __builtin_amdgcn_mfma_f32_16x16x32_bf16(ar3, bfr[1][kk], s1[3], 0, 0, 0);
    }
    __builtin_amdgcn_s_setprio(0);
    pk8 p00, p01, p10, p11;
    p00.u[0] = pkrelu(s0[0][0], s0[0][1]); p00.u[1] = pkrelu(s0[0][2], s0[0][3]);
    p00.u[2] = pkrelu(s0[1][0], s0[1][1]); p00.u[3] = pkrelu(s0[1][2], s0[1][3]);
    p01.u[0] = pkrelu(s1[0][0], s1[0][1]); p01.u[1] = pkrelu(s1[0][2], s1[0][3]);
    p01.u[2] = pkrelu(s1[1][0], s1[1][1]); p01.u[3] = pkrelu(s1[1][2], s1[1][3]);
    p10.u[0] = pkrelu(s0[2][0], s0[2][1]); p10.u[1] = pkrelu(s0[2][2], s0[2][3]);
    p10.u[2] = pkrelu(s0[3][0], s0[3][1]); p10.u[3] = pkrelu(s0[3][2], s0[3][3]);
    p11.u[0] = pkrelu(s1[2][0], s1[2][1]); p11.u[1] = pkrelu(s1[2][2], s1[2][3]);
    p11.u[2] = pkrelu(s1[3][0], s1[3][1]); p11.u[3] = pkrelu(s1[3][2], s1[3][3]);
    __builtin_amdgcn_s_setprio(1);
#pragma unroll
    for (int n = 0; n < 8; ++n) {
      bf16x8 bb0 = *(const bf16x8*)&Ys[ysb[0] + n * 1024];
      bf16x8 bb1 = *(const bf16x8*)&Ys[ysb[1] + n * 1024];
      oacc0[n] = __builtin_amdgcn_mfma_f32_16x16x32_bf16(p00.v, bb0, oacc0[n], 0, 0, 0);
      oacc1[n] = __builtin_amdgcn_mfma_f32_16x16x32_bf16(p01.v, bb0, oacc1[n], 0, 0, 0);
      oacc0[n] = __builtin_amdgcn_mfma_f32_16x16x32_bf16(p10.v, bb1, oacc0[n], 0, 0, 0);
      oacc1[n] = __builtin_amdgcn_mfma_f32_16x16x32_bf16(p11.v, bb1, oacc1[n], 0, 0, 0);
    }
    __builtin_amdgcn_s_setprio(0);
    ++ybuf; if (ybuf == 3) ybuf = 0;
  }

  // epilogue: oacc -> bf16 via LDS (XjB 32 KB), XOR-swizzled both sides.
  __syncthreads();
  unsigned short* sb = &XjB[0][0];  // 128 x 128 bf16 (swizzled granules)
#pragma unroll
  for (int m = 0; m < 2; ++m)
#pragma unroll
    for (int n = 0; n < 8; ++n)
#pragma unroll
      for (int r = 0; r < 4; ++r) {
        int row = wv * 32 + m * 16 + g * 4 + r;
        int col = n * 16 + l15;
        sb[row * 128 + (((col >> 3) ^ (row & 7)) << 3) + (col & 7)] =
            f2bf(m == 0 ? oacc0[n][r] : oacc1[n][r]);
      }
  __syncthreads();
  for (int c = tid; c < 2048; c += 256) {
    int row = c >> 4, gq = c & 15;
    *(uint4*)&opart[((size_t)zc * (BN * NN) + b * NN + i0 + row) * DD + gq * 8] =
        *(const uint4*)&sb[row * 128 + ((gq ^ (row & 7)) << 3)];
  }
}

// ---- kernel 5 (MFMA): out = tanh((sum_zc opart) @ W^T + bias) + x ----
__global__ __launch_bounds__(256) void k_final(const unsigned short* __restrict__ opart,
                                               int jc,
                                               const float* __restrict__ W,
                                               const float* __restrict__ bias,
                                               const float* __restrict__ x,
                                               float* __restrict__ out) {
  __shared__ unsigned short Wb[128 * 128];    // 32 KB bf16, swizzled
  __shared__ unsigned short PreS[32 * 128];   // 8 KB bf16, swizzled
  const int tid = threadIdx.x, lane = tid & 63, wv = tid >> 6;
  const int g = lane >> 4;
  const int r0 = blockIdx.x * 32;

  {
    int h = tid >> 1, k0h = (tid & 1) * 8;
    const float* wr = W + h * 128 + k0h * 8;
#pragma unroll
    for (int q = 0; q < 8; ++q) {
      float4 v0 = *(const float4*)(wr + q * 8);
      float4 v1 = *(const float4*)(wr + q * 8 + 4);
      uint4 o;
      o.x = cvtpk(v0.x, v0.y); o.y = cvtpk(v0.z, v0.w);
      o.z = cvtpk(v1.x, v1.y); o.w = cvtpk(v1.z, v1.w);
      int gq = k0h + q;
      *(uint4*)&Wb[h * 128 + ((gq ^ (h & 7)) << 3)] = o;
    }
  }
  for (int c = tid; c < 512; c += 256) {
    int row = c >> 4, gq = c & 15;
    float s[8] = {0.f, 0.f, 0.f, 0.f, 0.f, 0.f, 0.f, 0.f};
    for (int ch = 0; ch < jc; ++ch) {
      uint4 pk = *(const uint4*)&opart[((size_t)ch * (BN * NN) + r0 + row) * DD + gq * 8];
      alignas(16) unsigned short us[8];
      *(uint4*)us = pk;
#pragma unroll
      for (int u = 0; u < 8; ++u) s[u] += bf2f(us[u]);
    }
    uint4 o;
    o.x = cvtpk(s[0], s[1]); o.y = cvtpk(s[2], s[3]);
    o.z = cvtpk(s[4], s[5]); o.w = cvtpk(s[6], s[7]);
    *(uint4*)&PreS[row * 128 + ((gq ^ (row & 7)) << 3)] = o;
  }
  __syncthreads();

  bf16x8 af[2][4], bf[2][4];
#pragma unroll
  for (int m = 0; m < 2; ++m)
#pragma unroll
    for (int kk = 0; kk < 4; ++kk) {
      int row = m * 16 + (lane & 15);
      af[m][kk] = *(const bf16x8*)&PreS[row * 128 + (((kk * 4 + g) ^ (row & 7)) << 3)];
    }
#pragma unroll
  for (int n = 0; n < 2; ++n)
#pragma unroll
    for (int kk = 0; kk < 4; ++kk) {
      int h = wv * 32 + n * 16 + (lane & 15);
      bf[n][kk] = *(const bf16x8*)&Wb[h * 128 + (((kk * 4 + g) ^ (h & 7)) << 3)];
    }

  f32x4 acc[2][2] = {};
#pragma unroll
  for (int kk = 0; kk < 4; ++kk) {
    acc[0][0] = __builtin_amdgcn_mfma_f32_16x16x32_bf16(af[0][kk], bf[0][kk], acc[0][0], 0, 0, 0);
    acc[0][1] = __builtin_amdgcn_mfma_f32_16x16x32_bf16(af[0][kk], bf[1][kk], acc[0][1], 0, 0, 0);
    acc[1][0] = __builtin_amdgcn_mfma_f32_16x16x32_bf16(af[1][kk], bf[0][kk], acc[1][0], 0, 0, 0);
    acc[1][1] = __builtin_amdgcn_mfma_f32_16x16x32_bf16(af[1][kk], bf[1][kk], acc[1][1], 0, 0, 0);
  }

  float bh0 = bias[wv * 32 + (lane & 15)];
  float bh1 = bias[wv * 32 + 16 + (lane & 15)];
#pragma unroll
  for (int m = 0; m < 2; ++m)
#pragma unroll
    for (int n = 0; n < 2; ++n)
#pragma unroll
      for (int r = 0; r < 4; ++r) {
        int row = r0 + m * 16 + g * 4 + r;
        int h = wv * 32 + n * 16 + (lane & 15);
        size_t idx = (size_t)row * 128 + h;
        out[idx] = tanhf(acc[m][n][r] + (n == 0 ? bh0 : bh1)) + x[idx];
      }
}

extern "C" void kernel_launch(void* const* d_in, const int* in_sizes, int n_in,
                              void* d_out, int out_size, void* d_ws, size_t ws_size,
                              hipStream_t stream) {
  (void)in_sizes; (void)n_in; (void)out_size;
  const float* x = (const float*)d_in[0];
  const float* W = (const float*)d_in[1];
  const float* bias = (const float*)d_in[2];
  float* out = (float*)d_out;
  char* ws = (char*)d_ws;
  unsigned short* xb = (unsigned short*)ws;                       // 4 MB @ 0
  unsigned short* yt = (unsigned short*)(ws + (4u << 20));        // 4 MB @ 4M
  float* colpart = (float*)(ws + (8u << 20));                     // 512 KB @ 8M
  unsigned short* opart = (unsigned short*)(ws + (9u << 20));     // jc*4 MB @ 9M

  const size_t need4 = (9u << 20) + 4u * (4u << 20);
  const int jc = (ws_size >= need4) ? 4 : 1;

  k_cvt<<<1024, 256, 0, stream>>>(x, xb);
  k_colsum<<<dim3(32, 4, 8), 256, 0, stream>>>(xb, colpart);
  k_ytrans<<<dim3(2, 64, 4), 256, 0, stream>>>(x, colpart, yt);
  k_pass2<<<dim3(32, 4, jc), 256, 0, stream>>>(xb, yt, opart, jc);
  k_final<<<512, 256, 0, stream>>>(opart, jc, W, bias, x, out);
}

// Round 18
// 80.042 us; speedup vs baseline: 1.4871x; 1.0209x over previous
//
#include <hip/hip_runtime.h>
#include <hip/hip_bf16.h>

#define BN 4
#define NN 4096
#define DD 128

typedef __attribute__((ext_vector_type(8))) __bf16 bf16x8;
typedef __attribute__((ext_vector_type(4))) float f32x4;

typedef union {
  bf16x8 v;
  unsigned int u[4];
  uint2 u2[2];
} pk8;

typedef __attribute__((address_space(1))) const unsigned int* gas_p;
typedef __attribute__((address_space(3))) unsigned int* las_p;

__device__ __forceinline__ void gload16(const void* g, void* l) {
  __builtin_amdgcn_global_load_lds((gas_p)g, (las_p)l, 16, 0, 0);
}
__device__ __forceinline__ void wait_vm0() {
  asm volatile("s_waitcnt vmcnt(0)" ::: "memory");
}
__device__ __forceinline__ void wait_vm4() {
  asm volatile("s_waitcnt vmcnt(4)" ::: "memory");
}
__device__ __forceinline__ void wait_vm12() {
  asm volatile("s_waitcnt vmcnt(12)" ::: "memory");
}
__device__ __forceinline__ unsigned int cvtpk(float lo, float hi) {
  unsigned int r;
  asm("v_cvt_pk_bf16_f32 %0, %1, %2" : "=v"(r) : "v"(lo), "v"(hi));
  return r;
}
__device__ __forceinline__ unsigned int pkrelu(float lo, float hi) {
  return cvtpk(fmaxf(lo, 0.f), fmaxf(hi, 0.f));
}

__device__ inline unsigned short f2bf(float f) {
  unsigned int u = __float_as_uint(f);
  unsigned int r = (u + 0x7FFFu + ((u >> 16) & 1u)) >> 16;
  return (unsigned short)r;
}
__device__ inline float bf2f(unsigned short s) {
  return __uint_as_float(((unsigned int)s) << 16);
}

// ---------------- kernel 1: cast x (fp32) -> xb (bf16) ----------------
__global__ __launch_bounds__(256) void k_cvt(const float* __restrict__ x,
                                             unsigned short* __restrict__ xb) {
  int i = (blockIdx.x * 256 + threadIdx.x) * 8;
  float4 a = *(const float4*)(x + i);
  float4 c = *(const float4*)(x + i + 4);
  uint4 o;
  o.x = cvtpk(a.x, a.y);
  o.y = cvtpk(a.z, a.w);
  o.z = cvtpk(c.x, c.y);
  o.w = cvtpk(c.z, c.w);
  *(uint4*)(xb + i) = o;
}

// ---- kernel 2: colpart[(ic*BN+b)][j] = sum_{i in chunk ic} relu(<x_i,x_j>) ----
// (round-12 proven version: LDS dbuf via global_load_lds, 4 blocks/CU)
__global__ __launch_bounds__(256, 4) void k_colsum(const unsigned short* __restrict__ xb,
                                                   float* __restrict__ colpart) {
  __shared__ unsigned short XiB[2][64 * 128];  // 32 KB
  const int b = blockIdx.y, j0 = blockIdx.x * 128, ic = blockIdx.z;
  const int tid = threadIdx.x, lane = tid & 63, wv = tid >> 6;
  const unsigned short* xbb = xb + b * NN * DD;
  const int g = lane >> 4;
  const int ibeg = ic * (NN / 8);
  const int nt = (NN / 8) / 64;  // 8

#pragma unroll
  for (int hb = 0; hb < 2; ++hb)
#pragma unroll
    for (int q = 0; q < 4; ++q) {
      int c = wv * 4 + q;
      int lr = c * 4 + g;
      int gsrc = (lane & 15) ^ (lr & 7);
      gload16(&xbb[(j0 + hb * 64 + lr) * 128 + gsrc * 8], &XiB[hb][c * 512]);
    }
  wait_vm0();
  __syncthreads();

  bf16x8 bfr[2][4];
#pragma unroll
  for (int ni = 0; ni < 2; ++ni)
#pragma unroll
    for (int kk = 0; kk < 4; ++kk) {
      int lr = (wv & 1) * 32 + ni * 16 + (lane & 15);
      bfr[ni][kk] = *(const bf16x8*)&XiB[wv >> 1][lr * 128 + (((kk * 4 + g) ^ (lr & 7)) << 3)];
    }
  __syncthreads();

#pragma unroll
  for (int q = 0; q < 4; ++q) {
    int c = wv * 4 + q;
    int lr = c * 4 + g;
    int gsrc = (lane & 15) ^ (lr & 7);
    gload16(&xbb[(ibeg + lr) * 128 + gsrc * 8], &XiB[1][c * 512]);
  }

  int basek[4];
#pragma unroll
  for (int kk = 0; kk < 4; ++kk)
    basek[kk] = (lane & 15) * 128 + (((kk * 4 + g) ^ (lane & 7)) << 3);

  float colacc0 = 0.f, colacc1 = 0.f;
  for (int t = 0; t < nt; ++t) {
    wait_vm0();
    __syncthreads();
    const int cur = (t + 1) & 1, nxt = t & 1;
    if (t + 1 < nt) {
      const int i1 = ibeg + (t + 1) * 64;
#pragma unroll
      for (int q = 0; q < 4; ++q) {
        int c = wv * 4 + q;
        int lr = c * 4 + g;
        int gsrc = (lane & 15) ^ (lr & 7);
        gload16(&xbb[(i1 + lr) * 128 + gsrc * 8], &XiB[nxt][c * 512]);
      }
    }
    f32x4 a0[4], a1[4];
#pragma unroll
    for (int mj = 0; mj < 4; ++mj) { a0[mj] = (f32x4){}; a1[mj] = (f32x4){}; }
    __builtin_amdgcn_s_setprio(1);
#pragma unroll
    for (int kk = 0; kk < 4; ++kk) {
      bf16x8 ar0 = *(const bf16x8*)&XiB[cur][basek[kk]];
      bf16x8 ar1 = *(const bf16x8*)&XiB[cur][basek[kk] + 1 * 2048];
      bf16x8 ar2 = *(const bf16x8*)&XiB[cur][basek[kk] + 2 * 2048];
      bf16x8 ar3 = *(const bf16x8*)&XiB[cur][basek[kk] + 3 * 2048];
      a0[0] = __builtin_amdgcn_mfma_f32_16x16x32_bf16(ar0, bfr[0][kk], a0[0], 0, 0, 0);
      a1[0] = __builtin_amdgcn_mfma_f32_16x16x32_bf16(ar0, bfr[1][kk], a1[0], 0, 0, 0);
      a0[1] = __builtin_amdgcn_mfma_f32_16x16x32_bf16(ar1, bfr[0][kk], a0[1], 0, 0, 0);
      a1[1] = __builtin_amdgcn_mfma_f32_16x16x32_bf16(ar1, bfr[1][kk], a1[1], 0, 0, 0);
      a0[2] = __builtin_amdgcn_mfma_f32_16x16x32_bf16(ar2, bfr[0][kk], a0[2], 0, 0, 0);
      a1[2] = __builtin_amdgcn_mfma_f32_16x16x32_bf16(ar2, bfr[1][kk], a1[2], 0, 0, 0);
      a0[3] = __builtin_amdgcn_mfma_f32_16x16x32_bf16(ar3, bfr[0][kk], a0[3], 0, 0, 0);
      a1[3] = __builtin_amdgcn_mfma_f32_16x16x32_bf16(ar3, bfr[1][kk], a1[3], 0, 0, 0);
    }
    __builtin_amdgcn_s_setprio(0);
    {
      float s0 = 0.f, s1 = 0.f;
#pragma unroll
      for (int mj = 0; mj < 4; ++mj)
#pragma unroll
        for (int r = 0; r < 4; ++r) {
          s0 += fmaxf(a0[mj][r], 0.f);
          s1 += fmaxf(a1[mj][r], 0.f);
        }
      s0 += __shfl_xor(s0, 16); s0 += __shfl_xor(s0, 32);
      s1 += __shfl_xor(s1, 16); s1 += __shfl_xor(s1, 32);
      colacc0 += s0; colacc1 += s1;
    }
  }
  if (lane < 16) {
    colpart[(ic * BN + b) * NN + j0 + wv * 32 + lane] = colacc0;
    colpart[(ic * BN + b) * NN + j0 + wv * 32 + 16 + lane] = colacc1;
  }
}

// ---- kernel 3: yt[b][d][jp] = bf16(x[b][perm(jp)][d] / colsum) ----
// j-order within each aligned 64-block is PERMUTED to pass2's PV k-map:
// position p = G*8+e holds j = (G>>2)*32 + (G&3)*4 + (e&3) + (e>>2)*16.
__global__ __launch_bounds__(256) void k_ytrans(const float* __restrict__ x,
                                                const float* __restrict__ colpart,
                                                unsigned short* __restrict__ yt) {
  __shared__ unsigned short T[64 * 72];
  const int b = blockIdx.z, j0 = blockIdx.y * 64, d0 = blockIdx.x * 64;
  const int tid = threadIdx.x;
  int jr = tid >> 2, q0 = (tid & 3) * 16;
  float cs = 0.f;
#pragma unroll
  for (int ic = 0; ic < 8; ++ic) cs += colpart[(ic * BN + b) * NN + j0 + jr];
  float inv = 1.0f / cs;
  const float* xr = x + (size_t)(b * NN + j0 + jr) * DD + d0 + q0;
#pragma unroll
  for (int q = 0; q < 4; ++q) {
    float4 v = *(const float4*)(xr + q * 4);
    int dc = q0 + q * 4;
    T[jr * 72 + dc + 0] = f2bf(v.x * inv);
    T[jr * 72 + dc + 1] = f2bf(v.y * inv);
    T[jr * 72 + dc + 2] = f2bf(v.z * inv);
    T[jr * 72 + dc + 3] = f2bf(v.w * inv);
  }
  __syncthreads();
  for (int c = tid; c < 512; c += 256) {
    int dr = c >> 3, jg = c & 7;
    alignas(16) unsigned short tmp[8];
#pragma unroll
    for (int u = 0; u < 8; ++u) {
      int jj = (jg >> 2) * 32 + (jg & 3) * 4 + (u & 3) + (u >> 2) * 16;
      tmp[u] = T[jj * 72 + dr];
    }
    *(uint4*)&yt[(size_t)(b * DD + d0 + dr) * NN + j0 + jg * 8] = *(const uint4*)tmp;
  }
}

// ---- kernel 4: opart[zc][b*NN+i][:] = sum_{j in chunk zc} relu(<x_i,x_j>) y[j][:] ----
// Software-pipelined: body t = { pack(S[t]) ; S[t+1] || PV[t] } — two
// independent MFMA chains per body. Same 1 barrier/iter, same vmcnt(4)
// discipline (in-flight at body top = {Ys[t], Xj[t+1], Ys[t+1]} = 12 loads).
__global__ __launch_bounds__(256, 2) void k_pass2(const unsigned short* __restrict__ xb,
                                                  const unsigned short* __restrict__ yt,
                                                  unsigned short* __restrict__ opart,
                                                  int jc) {
  __shared__ unsigned short XjB[2][64 * 128];  // 32 KB (Xi in prologue; sb in epilogue)
  __shared__ unsigned short YsB[3][128 * 64];  // 48 KB, triple buffer
  const int b = blockIdx.y, i0 = blockIdx.x * 128, zc = blockIdx.z;
  const int tid = threadIdx.x, lane = tid & 63, wv = tid >> 6;
  const unsigned short* xbb = xb + b * NN * DD;
  const unsigned short* ytb = yt + (size_t)b * DD * NN;
  const int g = lane >> 4, l15 = lane & 15;

  const int jspan = NN / jc;
  const int jbeg = zc * jspan;
  const int nt = jspan / 64;

  // prologue: Xi 128 rows -> XjB[0] + XjB[1]
#pragma unroll
  for (int hb = 0; hb < 2; ++hb)
#pragma unroll
    for (int q = 0; q < 4; ++q) {
      int c = wv * 4 + q;
      int lr = c * 4 + g;
      int gsrc = l15 ^ (lr & 7);
      gload16(&xbb[(i0 + hb * 64 + lr) * 128 + gsrc * 8], &XjB[hb][c * 512]);
    }
  wait_vm0();
  __syncthreads();

  // Xi B-frags: wave's 32 i = wv*32 + ni*16 + l15
  bf16x8 bfr[2][4];
#pragma unroll
  for (int ni = 0; ni < 2; ++ni)
#pragma unroll
    for (int kk = 0; kk < 4; ++kk) {
      int lr = (wv & 1) * 32 + ni * 16 + l15;
      bfr[ni][kk] = *(const bf16x8*)&XjB[wv >> 1][lr * 128 + (((kk * 4 + g) ^ (lr & 7)) << 3)];
    }
  __syncthreads();  // XjB free

  // issue (oldest-first): Xj0, Ys0, Xj1, Ys1
#pragma unroll
  for (int q = 0; q < 4; ++q) {
    int c = wv * 4 + q;
    int lr = c * 4 + g;
    int gsrc = l15 ^ (lr & 7);
    gload16(&xbb[(jbeg + lr) * 128 + gsrc * 8], &XjB[0][c * 512]);
  }
#pragma unroll
  for (int q = 0; q < 4; ++q) {
    int c = wv * 4 + q;
    int dr = c * 8 + (lane >> 3);
    int gsrc = (lane & 7) ^ (dr & 7);
    gload16(&ytb[(size_t)dr * NN + jbeg + gsrc * 8], &YsB[0][c * 512]);
  }
  if (1 < nt) {
#pragma unroll
    for (int q = 0; q < 4; ++q) {
      int c = wv * 4 + q;
      int lr = c * 4 + g;
      int gsrc = l15 ^ (lr & 7);
      gload16(&xbb[(jbeg + 64 + lr) * 128 + gsrc * 8], &XjB[1][c * 512]);
    }
#pragma unroll
    for (int q = 0; q < 4; ++q) {
      int c = wv * 4 + q;
      int dr = c * 8 + (lane >> 3);
      int gsrc = (lane & 7) ^ (dr & 7);
      gload16(&ytb[(size_t)dr * NN + jbeg + 64 + gsrc * 8], &YsB[1][c * 512]);
    }
  }

  int xjb[4];   // S^T A-frag bases in Xj tile
#pragma unroll
  for (int kk = 0; kk < 4; ++kk)
    xjb[kk] = l15 * 128 + (((kk * 4 + g) ^ (l15 & 7)) << 3);
  int ysb[2];   // PV B b128 bases (permuted yt)
#pragma unroll
  for (int c = 0; c < 2; ++c)
    ysb[c] = l15 * 64 + (((c * 4 + g) ^ (l15 & 7)) << 3);

  f32x4 oacc0[8], oacc1[8];
#pragma unroll
  for (int n = 0; n < 8; ++n) { oacc0[n] = (f32x4){}; oacc1[n] = (f32x4){}; }

  // ---- prologue compute: S[0] from XjB[0] ----
  f32x4 s0[4], s1[4];
#pragma unroll
  for (int mj = 0; mj < 4; ++mj) { s0[mj] = (f32x4){}; s1[mj] = (f32x4){}; }
  if (nt > 1) wait_vm12(); else wait_vm0();  // Xj0 landed (oldest 4 of 16/8)
  __syncthreads();
  {
    const unsigned short* Xj = XjB[0];
    __builtin_amdgcn_s_setprio(1);
#pragma unroll
    for (int kk = 0; kk < 4; ++kk) {
      bf16x8 ar0 = *(const bf16x8*)&Xj[xjb[kk]];
      bf16x8 ar1 = *(const bf16x8*)&Xj[xjb[kk] + 1 * 2048];
      bf16x8 ar2 = *(const bf16x8*)&Xj[xjb[kk] + 2 * 2048];
      bf16x8 ar3 = *(const bf16x8*)&Xj[xjb[kk] + 3 * 2048];
      s0[0] = __builtin_amdgcn_mfma_f32_16x16x32_bf16(ar0, bfr[0][kk], s0[0], 0, 0, 0);
      s1[0] = __builtin_amdgcn_mfma_f32_16x16x32_bf16(ar0, bfr[1][kk], s1[0], 0, 0, 0);
      s0[1] = __builtin_amdgcn_mfma_f32_16x16x32_bf16(ar1, bfr[0][kk], s0[1], 0, 0, 0);
      s1[1] = __builtin_amdgcn_mfma_f32_16x16x32_bf16(ar1, bfr[1][kk], s1[1], 0, 0, 0);
      s0[2] = __builtin_amdgcn_mfma_f32_16x16x32_bf16(ar2, bfr[0][kk], s0[2], 0, 0, 0);
      s1[2] = __builtin_amdgcn_mfma_f32_16x16x32_bf16(ar2, bfr[1][kk], s1[2], 0, 0, 0);
      s0[3] = __builtin_amdgcn_mfma_f32_16x16x32_bf16(ar3, bfr[0][kk], s0[3], 0, 0, 0);
      s1[3] = __builtin_amdgcn_mfma_f32_16x16x32_bf16(ar3, bfr[1][kk], s1[3], 0, 0, 0);
    }
    __builtin_amdgcn_s_setprio(0);
  }

  int ybuf = 0;  // Ys slot of tile t
  for (int t = 0; t < nt; ++t) {
    // in-flight at top: {Ys[t], Xj[t+1], Ys[t+1]} -> retire oldest 8
    if (t + 1 < nt) wait_vm4(); else wait_vm0();
    __syncthreads();
    // issue tile t+2 (Xj first, then Ys — oldest-first discipline)
    if (t + 2 < nt) {
      const int j2 = jbeg + (t + 2) * 64;
#pragma unroll
      for (int q = 0; q < 4; ++q) {
        int c = wv * 4 + q;
        int lr = c * 4 + g;
        int gsrc = l15 ^ (lr & 7);
        gload16(&xbb[(j2 + lr) * 128 + gsrc * 8], &XjB[t & 1][c * 512]);
      }
      int nb = ybuf + 2; if (nb >= 3) nb -= 3;
#pragma unroll
      for (int q = 0; q < 4; ++q) {
        int c = wv * 4 + q;
        int dr = c * 8 + (lane >> 3);
        int gsrc = (lane & 7) ^ (dr & 7);
        gload16(&ytb[(size_t)dr * NN + j2 + gsrc * 8], &YsB[nb][c * 512]);
      }
    }
    // pack P[t] from S[t] accumulators (frees s regs)
    pk8 p00, p01, p10, p11;
    p00.u[0] = pkrelu(s0[0][0], s0[0][1]); p00.u[1] = pkrelu(s0[0][2], s0[0][3]);
    p00.u[2] = pkrelu(s0[1][0], s0[1][1]); p00.u[3] = pkrelu(s0[1][2], s0[1][3]);
    p01.u[0] = pkrelu(s1[0][0], s1[0][1]); p01.u[1] = pkrelu(s1[0][2], s1[0][3]);
    p01.u[2] = pkrelu(s1[1][0], s1[1][1]); p01.u[3] = pkrelu(s1[1][2], s1[1][3]);
    p10.u[0] = pkrelu(s0[2][0], s0[2][1]); p10.u[1] = pkrelu(s0[2][2], s0[2][3]);
    p10.u[2] = pkrelu(s0[3][0], s0[3][1]); p10.u[3] = pkrelu(s0[3][2], s0[3][3]);
    p11.u[0] = pkrelu(s1[2][0], s1[2][1]); p11.u[1] = pkrelu(s1[2][2], s1[2][3]);
    p11.u[2] = pkrelu(s1[3][0], s1[3][1]); p11.u[3] = pkrelu(s1[3][2], s1[3][3]);

    const unsigned short* Ys = YsB[ybuf];
    __builtin_amdgcn_s_setprio(1);
    // S[t+1] (independent chain) — from XjB[(t+1)&1]
    if (t + 1 < nt) {
      const unsigned short* Xj = XjB[(t + 1) & 1];
#pragma unroll
      for (int mj = 0; mj < 4; ++mj) { s0[mj] = (f32x4){}; s1[mj] = (f32x4){}; }
#pragma unroll
      for (int kk = 0; kk < 4; ++kk) {
        bf16x8 ar0 = *(const bf16x8*)&Xj[xjb[kk]];
        bf16x8 ar1 = *(const bf16x8*)&Xj[xjb[kk] + 1 * 2048];
        bf16x8 ar2 = *(const bf16x8*)&Xj[xjb[kk] + 2 * 2048];
        bf16x8 ar3 = *(const bf16x8*)&Xj[xjb[kk] + 3 * 2048];
        s0[0] = __builtin_amdgcn_mfma_f32_16x16x32_bf16(ar0, bfr[0][kk], s0[0], 0, 0, 0);
        s1[0] = __builtin_amdgcn_mfma_f32_16x16x32_bf16(ar0, bfr[1][kk], s1[0], 0, 0, 0);
        s0[1] = __builtin_amdgcn_mfma_f32_16x16x32_bf16(ar1, bfr[0][kk], s0[1], 0, 0, 0);
        s1[1] = __builtin_amdgcn_mfma_f32_16x16x32_bf16(ar1, bfr[1][kk], s1[1], 0, 0, 0);
        s0[2] = __builtin_amdgcn_mfma_f32_16x16x32_bf16(ar2, bfr[0][kk], s0[2], 0, 0, 0);
        s1[2] = __builtin_amdgcn_mfma_f32_16x16x32_bf16(ar2, bfr[1][kk], s1[2], 0, 0, 0);
        s0[3] = __builtin_amdgcn_mfma_f32_16x16x32_bf16(ar3, bfr[0][kk], s0[3], 0, 0, 0);
        s1[3] = __builtin_amdgcn_mfma_f32_16x16x32_bf16(ar3, bfr[1][kk], s1[3], 0, 0, 0);
      }
    }
    // PV[t] (independent chain) — from YsB[ybuf] with p
#pragma unroll
    for (int n = 0; n < 8; ++n) {
      bf16x8 bb0 = *(const bf16x8*)&Ys[ysb[0] + n * 1024];
      bf16x8 bb1 = *(const bf16x8*)&Ys[ysb[1] + n * 1024];
      oacc0[n] = __builtin_amdgcn_mfma_f32_16x16x32_bf16(p00.v, bb0, oacc0[n], 0, 0, 0);
      oacc1[n] = __builtin_amdgcn_mfma_f32_16x16x32_bf16(p01.v, bb0, oacc1[n], 0, 0, 0);
      oacc0[n] = __builtin_amdgcn_mfma_f32_16x16x32_bf16(p10.v, bb1, oacc0[n], 0, 0, 0);
      oacc1[n] = __builtin_amdgcn_mfma_f32_16x16x32_bf16(p11.v, bb1, oacc1[n], 0, 0, 0);
    }
    __builtin_amdgcn_s_setprio(0);
    ++ybuf; if (ybuf == 3) ybuf = 0;
  }

  // epilogue: oacc -> bf16 via LDS (XjB 32 KB), XOR-swizzled both sides.
  __syncthreads();
  unsigned short* sb = &XjB[0][0];  // 128 x 128 bf16 (swizzled granules)
#pragma unroll
  for (int m = 0; m < 2; ++m)
#pragma unroll
    for (int n = 0; n < 8; ++n)
#pragma unroll
      for (int r = 0; r < 4; ++r) {
        int row = wv * 32 + m * 16 + g * 4 + r;
        int col = n * 16 + l15;
        sb[row * 128 + (((col >> 3) ^ (row & 7)) << 3) + (col & 7)] =
            f2bf(m == 0 ? oacc0[n][r] : oacc1[n][r]);
      }
  __syncthreads();
  for (int c = tid; c < 2048; c += 256) {
    int row = c >> 4, gq = c & 15;
    *(uint4*)&opart[((size_t)zc * (BN * NN) + b * NN + i0 + row) * DD + gq * 8] =
        *(const uint4*)&sb[row * 128 + ((gq ^ (row & 7)) << 3)];
  }
}

// ---- kernel 5 (MFMA): out = tanh((sum_zc opart) @ W^T + bias) + x ----
__global__ __launch_bounds__(256) void k_final(const unsigned short* __restrict__ opart,
                                               int jc,
                                               const float* __restrict__ W,
                                               const float* __restrict__ bias,
                                               const float* __restrict__ x,
                                               float* __restrict__ out) {
  __shared__ unsigned short Wb[128 * 128];    // 32 KB bf16, swizzled
  __shared__ unsigned short PreS[32 * 128];   // 8 KB bf16, swizzled
  const int tid = threadIdx.x, lane = tid & 63, wv = tid >> 6;
  const int g = lane >> 4;
  const int r0 = blockIdx.x * 32;

  {
    int h = tid >> 1, k0h = (tid & 1) * 8;
    const float* wr = W + h * 128 + k0h * 8;
#pragma unroll
    for (int q = 0; q < 8; ++q) {
      float4 v0 = *(const float4*)(wr + q * 8);
      float4 v1 = *(const float4*)(wr + q * 8 + 4);
      uint4 o;
      o.x = cvtpk(v0.x, v0.y); o.y = cvtpk(v0.z, v0.w);
      o.z = cvtpk(v1.x, v1.y); o.w = cvtpk(v1.z, v1.w);
      int gq = k0h + q;
      *(uint4*)&Wb[h * 128 + ((gq ^ (h & 7)) << 3)] = o;
    }
  }
  for (int c = tid; c < 512; c += 256) {
    int row = c >> 4, gq = c & 15;
    float s[8] = {0.f, 0.f, 0.f, 0.f, 0.f, 0.f, 0.f, 0.f};
    for (int ch = 0; ch < jc; ++ch) {
      uint4 pk = *(const uint4*)&opart[((size_t)ch * (BN * NN) + r0 + row) * DD + gq * 8];
      alignas(16) unsigned short us[8];
      *(uint4*)us = pk;
#pragma unroll
      for (int u = 0; u < 8; ++u) s[u] += bf2f(us[u]);
    }
    uint4 o;
    o.x = cvtpk(s[0], s[1]); o.y = cvtpk(s[2], s[3]);
    o.z = cvtpk(s[4], s[5]); o.w = cvtpk(s[6], s[7]);
    *(uint4*)&PreS[row * 128 + ((gq ^ (row & 7)) << 3)] = o;
  }
  __syncthreads();

  bf16x8 af[2][4], bf[2][4];
#pragma unroll
  for (int m = 0; m < 2; ++m)
#pragma unroll
    for (int kk = 0; kk < 4; ++kk) {
      int row = m * 16 + (lane & 15);
      af[m][kk] = *(const bf16x8*)&PreS[row * 128 + (((kk * 4 + g) ^ (row & 7)) << 3)];
    }
#pragma unroll
  for (int n = 0; n < 2; ++n)
#pragma unroll
    for (int kk = 0; kk < 4; ++kk) {
      int h = wv * 32 + n * 16 + (lane & 15);
      bf[n][kk] = *(const bf16x8*)&Wb[h * 128 + (((kk * 4 + g) ^ (h & 7)) << 3)];
    }

  f32x4 acc[2][2] = {};
#pragma unroll
  for (int kk = 0; kk < 4; ++kk) {
    acc[0][0] = __builtin_amdgcn_mfma_f32_16x16x32_bf16(af[0][kk], bf[0][kk], acc[0][0], 0, 0, 0);
    acc[0][1] = __builtin_amdgcn_mfma_f32_16x16x32_bf16(af[0][kk], bf[1][kk], acc[0][1], 0, 0, 0);
    acc[1][0] = __builtin_amdgcn_mfma_f32_16x16x32_bf16(af[1][kk], bf[0][kk], acc[1][0], 0, 0, 0);
    acc[1][1] = __builtin_amdgcn_mfma_f32_16x16x32_bf16(af[1][kk], bf[1][kk], acc[1][1], 0, 0, 0);
  }

  float bh0 = bias[wv * 32 + (lane & 15)];
  float bh1 = bias[wv * 32 + 16 + (lane & 15)];
#pragma unroll
  for (int m = 0; m < 2; ++m)
#pragma unroll
    for (int n = 0; n < 2; ++n)
#pragma unroll
      for (int r = 0; r < 4; ++r) {
        int row = r0 + m * 16 + g * 4 + r;
        int h = wv * 32 + n * 16 + (lane & 15);
        size_t idx = (size_t)row * 128 + h;
        out[idx] = tanhf(acc[m][n][r] + (n == 0 ? bh0 : bh1)) + x[idx];
      }
}

extern "C" void kernel_launch(void* const* d_in, const int* in_sizes, int n_in,
                              void* d_out, int out_size, void* d_ws, size_t ws_size,
                              hipStream_t stream) {
  (void)in_sizes; (void)n_in; (void)out_size;
  const float* x = (const float*)d_in[0];
  const float* W = (const float*)d_in[1];
  const float* bias = (const float*)d_in[2];
  float* out = (float*)d_out;
  char* ws = (char*)d_ws;
  unsigned short* xb = (unsigned short*)ws;                       // 4 MB @ 0
  unsigned short* yt = (unsigned short*)(ws + (4u << 20));        // 4 MB @ 4M
  float* colpart = (float*)(ws + (8u << 20));                     // 512 KB @ 8M
  unsigned short* opart = (unsigned short*)(ws + (9u << 20));     // jc*4 MB @ 9M

  const size_t need4 = (9u << 20) + 4u * (4u << 20);
  const int jc = (ws_size >= need4) ? 4 : 1;

  k_cvt<<<1024, 256, 0, stream>>>(x, xb);
  k_colsum<<<dim3(32, 4, 8), 256, 0, stream>>>(xb, colpart);
  k_ytrans<<<dim3(2, 64, 4), 256, 0, stream>>>(x, colpart, yt);
  k_pass2<<<dim3(32, 4, jc), 256, 0, stream>>>(xb, yt, opart, jc);
  k_final<<<512, 256, 0, stream>>>(opart, jc, W, bias, x, out);
}